// Round 6
// baseline (316.755 us; speedup 1.0000x reference)
//
#include <hip/hip_runtime.h>

#define BB 4
#define TT 2048
#define CC 1024
#define HH 16
#define DD 64

typedef unsigned short u16;
typedef unsigned int u32;
typedef __bf16 bf16;
typedef __attribute__((ext_vector_type(8))) bf16 bf16x8;
typedef __attribute__((ext_vector_type(8))) u16 u16x8;
typedef __attribute__((ext_vector_type(4))) u16 u16x4;
typedef __attribute__((ext_vector_type(4))) float f32x4;

static __device__ __forceinline__ u16 f2b(float f) {
  unsigned u = __builtin_bit_cast(unsigned, f);
  u += 0x7fffu + ((u >> 16) & 1u);
  return (u16)(u >> 16);
}
static __device__ __forceinline__ u16 bfc(float f) {
  return __builtin_bit_cast(u16, (__bf16)f);
}
static __device__ __forceinline__ u32 pkbf(float a, float b) {
  return (u32)bfc(a) | ((u32)bfc(b) << 16);
}

// ---------------- fp32 -> bf16 bulk convert (8 elems/thread) ----------------
__global__ void cvt_bf16_kernel(const float* __restrict__ src, u16* __restrict__ dst, int n8) {
  int i = blockIdx.x * blockDim.x + threadIdx.x;
  if (i >= n8) return;
  const float4* p4 = reinterpret_cast<const float4*>(src) + (size_t)i * 2;
  float4 a = p4[0], b = p4[1];
  u16x8 o;
  o[0] = f2b(a.x); o[1] = f2b(a.y); o[2] = f2b(a.z); o[3] = f2b(a.w);
  o[4] = f2b(b.x); o[5] = f2b(b.y); o[6] = f2b(b.z); o[7] = f2b(b.w);
  *reinterpret_cast<u16x8*>(dst + (size_t)i * 8) = o;
}

// ------------- W[k][n] fp32  ->  Wt[n][k] bf16  (32x32 LDS tile) -------------
__global__ void transp_w_kernel(const float* __restrict__ w0, const float* __restrict__ w1,
                                const float* __restrict__ w2, const float* __restrict__ w3,
                                u16* __restrict__ wqkvT, u16* __restrict__ wpT) {
  __shared__ float t[32][33];
  int z = blockIdx.z;
  const float* src = z == 0 ? w0 : z == 1 ? w1 : z == 2 ? w2 : w3;
  u16* dst = z < 3 ? wqkvT + (size_t)z * CC * CC : wpT;
  int k0 = blockIdx.x * 32, n0 = blockIdx.y * 32;
  int tx = threadIdx.x & 31, ty = threadIdx.x >> 5;
#pragma unroll
  for (int i = 0; i < 4; ++i)
    t[ty + i * 8][tx] = src[(size_t)(k0 + ty + i * 8) * CC + n0 + tx];
  __syncthreads();
#pragma unroll
  for (int i = 0; i < 4; ++i)
    dst[(size_t)(n0 + ty + i * 8) * CC + k0 + tx] = f2b(t[tx][ty + i * 8]);
}

// --------- mask prep: gm[b][t] = 0 / -1e30; fwords[b] bit kt = chunk-all-valid ---------
__global__ void mask_prep_kernel(const int* __restrict__ am, float* __restrict__ gm,
                                 u32* __restrict__ fwords) {
  __shared__ u32 sf[32];
  int b = blockIdx.x;
  int lane = threadIdx.x & 63, w = threadIdx.x >> 6;
#pragma unroll
  for (int j = 0; j < 8; ++j) {
    int c = w * 8 + j;
    int i = c * 64 + lane;
    int v = am[b * TT + i];
    gm[b * TT + i] = v ? 0.f : -1e30f;
    unsigned long long bal = __ballot(v != 0);
    if (lane == 0) sf[c] = (bal == ~0ull) ? 1u : 0u;
  }
  __syncthreads();
  if (threadIdx.x == 0) {
    u32 fw = 0;
    for (int c = 0; c < 32; ++c) fw |= sf[c] << c;
    fwords[b] = fw;
  }
}

// ---------------- bf16 GEMM: C[m][n] = sum_k A[m][k]*Bt[n][k] ----------------
// 128x128 tile, BK=32, 4 waves, 16x16x32 MFMA, global_load_lds.
// MODE 0: QKV epilogue -> Q,K scatter to [B,H,T,D]; V to [B,H,D,T] (transposed)
// MODE 1: fp32 out[m*N+n] = acc + bias[n]
template <int MODE>
__global__ __launch_bounds__(256) void gemm_bt_kernel(
    const u16* __restrict__ A, const u16* __restrict__ Bt, int K, int N,
    const float* __restrict__ b0, const float* __restrict__ b1, const float* __restrict__ b2,
    u16* __restrict__ q_out, u16* __restrict__ k_out, u16* __restrict__ v_out,
    float* __restrict__ f_out) {
  __shared__ u16 As[128 * 32];
  __shared__ u16 Bs[128 * 32];
  const int tid = threadIdx.x, lane = tid & 63, w = tid >> 6;
  const int wm = w >> 1, wn = w & 1;
  const int m0 = blockIdx.x * 128, n0 = blockIdx.y * 128;
  const int lrow = lane >> 2, lcol = (lane & 3) * 8;
  f32x4 acc[4][4] = {};

  for (int k0 = 0; k0 < K; k0 += 32) {
    if (k0) __syncthreads();
#pragma unroll
    for (int r = 0; r < 2; ++r) {
      int row = r * 64 + w * 16 + lrow;
      __builtin_amdgcn_global_load_lds(
          (const __attribute__((address_space(1))) void*)(A + (size_t)(m0 + row) * K + k0 + lcol),
          (__attribute__((address_space(3))) void*)(As + (r * 64 + w * 16) * 32),
          16, 0, 0);
      __builtin_amdgcn_global_load_lds(
          (const __attribute__((address_space(1))) void*)(Bt + (size_t)(n0 + row) * K + k0 + lcol),
          (__attribute__((address_space(3))) void*)(Bs + (r * 64 + w * 16) * 32),
          16, 0, 0);
    }
    __syncthreads();
    bf16x8 af[4], bfr[4];
#pragma unroll
    for (int i = 0; i < 4; ++i) {
      af[i] = *reinterpret_cast<const bf16x8*>(&As[(wm * 64 + i * 16 + (lane & 15)) * 32 + (lane >> 4) * 8]);
      bfr[i] = *reinterpret_cast<const bf16x8*>(&Bs[(wn * 64 + i * 16 + (lane & 15)) * 32 + (lane >> 4) * 8]);
    }
#pragma unroll
    for (int i = 0; i < 4; ++i)
#pragma unroll
      for (int j = 0; j < 4; ++j)
        acc[i][j] = __builtin_amdgcn_mfma_f32_16x16x32_bf16(af[i], bfr[j], acc[i][j], 0, 0, 0);
  }

  const int mrow = m0 + wm * 64;
  const int ncol = n0 + wn * 64;
  if (MODE == 0) {
    const int g = n0 >> 10;  // 0:Q 1:K 2:V (uniform per block)
    const float* bias = g == 0 ? b0 : g == 1 ? b1 : b2;
    if (g < 2) {
      u16* dst = g == 0 ? q_out : k_out;
#pragma unroll
      for (int i = 0; i < 4; ++i)
#pragma unroll
        for (int j = 0; j < 4; ++j)
#pragma unroll
          for (int r = 0; r < 4; ++r) {
            int m = mrow + i * 16 + (lane >> 4) * 4 + r;
            int n = ncol + j * 16 + (lane & 15);
            float v = acc[i][j][r] + bias[n & 1023];
            int b = m >> 11, t = m & 2047;
            int h = (n >> 6) & 15, d = n & 63;
            dst[(((size_t)(b * HH + h)) * TT + t) * DD + d] = f2b(v);
          }
    } else {
      // V transposed: [B,H,D,T]; 4 consecutive t per lane -> 8B store
#pragma unroll
      for (int i = 0; i < 4; ++i)
#pragma unroll
        for (int j = 0; j < 4; ++j) {
          int n = ncol + j * 16 + (lane & 15);
          int h = (n >> 6) & 15, d = n & 63;
          float bias_v = bias[n & 1023];
          int mb = mrow + i * 16 + (lane >> 4) * 4;
          int b = mb >> 11, t = mb & 2047;
          u16x4 vv;
#pragma unroll
          for (int r = 0; r < 4; ++r) vv[r] = f2b(acc[i][j][r] + bias_v);
          *reinterpret_cast<u16x4*>(v_out + (((size_t)(b * HH + h)) * DD + d) * TT + t) = vv;
        }
    }
  } else {
#pragma unroll
    for (int i = 0; i < 4; ++i)
#pragma unroll
      for (int j = 0; j < 4; ++j)
#pragma unroll
        for (int r = 0; r < 4; ++r) {
          int m = mrow + i * 16 + (lane >> 4) * 4 + r;
          int n = ncol + j * 16 + (lane & 15);
          f_out[(size_t)m * N + n] = acc[i][j][r] + b0[n];
        }
  }
}

// ------------- causal flash attention: swapped operands + split-kv wave pairs -------------
// S^T = mfma(K,Q), O^T = mfma(V^T,P^T). Each pair-slot (q-tiles iw & 63-iw) is handled
// by TWO waves interleaving kv tiles (even/odd) -> 4096 waves = 4/SIMD for latency
// hiding. Partials (o,m,l) merged lane-wise through LDS once per phase.
__global__ __launch_bounds__(256, 4) void attn_kernel(
    const u16* __restrict__ Q, const u16* __restrict__ K, const u16* __restrict__ Vt,
    const float* __restrict__ gm, const u32* __restrict__ fwords, u16* __restrict__ Y) {
  __shared__ u16 Pls[4][32 * 72];     // per-wave P buffer [32 q][64 kv], stride 72
  __shared__ float Mg[2][64][37];     // per-slot merge buffer [lane][32 o + m0 m1 l0 l1]
  const int flat = blockIdx.x;
  const int xcd = flat & 7, idx = flat >> 3;  // idx 0..127
  const int bh = xcd * 8 + (idx & 7);         // 8 heads per XCD (K/V L2 residency)
  const int jb = idx >> 3;                    // 0..15 block-slot within head
  const int b = bh >> 4, h = bh & 15;
  const int lane = threadIdx.x & 63, w = threadIdx.x >> 6;
  const int slotL = w >> 1;   // local slot 0,1
  const int par = w & 1;      // kv tile parity for this wave
  const int iw = jb * 2 + slotL;  // global pair-slot 0..31
  const int lq = lane & 15, g = lane >> 4;
  const u16* Qb = Q + (size_t)bh * TT * DD;
  const u16* Kb = K + (size_t)bh * TT * DD;
  const u16* Vb = Vt + (size_t)bh * DD * TT;
  u16* Pw = &Pls[w][0];
  const u32 fw = fwords[b];
  const float cs = 0.125f * 1.44269504089f;  // scale * log2(e)

  for (int phase = 0; phase < 2; ++phase) {
    const int qt = phase == 0 ? iw : 63 - iw;
    const int q0 = qt * 32;
    const int nkt = (qt >> 1) + 1;  // equal for both slots in this block (qt pair 2j,2j+1)

    bf16x8 qf[2][2];
#pragma unroll
    for (int n = 0; n < 2; ++n)
#pragma unroll
      for (int ks = 0; ks < 2; ++ks)
        qf[n][ks] = *reinterpret_cast<const bf16x8*>(
            Qb + (size_t)(q0 + n * 16 + lq) * DD + ks * 32 + g * 8);

    f32x4 o[4][2] = {};  // O^T: row d = nd*16+4g+r, col q = n*16+lq
    float mrun[2] = {-1e30f, -1e30f};
    float lrun[2] = {0.f, 0.f};  // per-lane partial (this lane's 16 kv)

    for (int kt = par; kt < nkt; kt += 2) {
      const int kv0 = kt * 64;
      bf16x8 kf[4][2];
#pragma unroll
      for (int m = 0; m < 4; ++m)
#pragma unroll
        for (int ks = 0; ks < 2; ++ks)
          kf[m][ks] = *reinterpret_cast<const bf16x8*>(
              Kb + (size_t)(kv0 + m * 16 + lq) * DD + ks * 32 + g * 8);

      f32x4 s[4][2] = {};
      __builtin_amdgcn_s_setprio(1);
#pragma unroll
      for (int m = 0; m < 4; ++m)
#pragma unroll
        for (int ks = 0; ks < 2; ++ks)
#pragma unroll
          for (int n = 0; n < 2; ++n)
            s[m][n] = __builtin_amdgcn_mfma_f32_16x16x32_bf16(kf[m][ks], qf[n][ks], s[m][n], 0, 0, 0);
      __builtin_amdgcn_s_setprio(0);

      // V^T fragments issued early: consumed only after softmax
      bf16x8 vf[2][4];
#pragma unroll
      for (int ks = 0; ks < 2; ++ks)
#pragma unroll
        for (int nd = 0; nd < 4; ++nd)
          vf[ks][nd] = *reinterpret_cast<const bf16x8*>(
              Vb + (size_t)(nd * 16 + lq) * TT + kv0 + ks * 32 + g * 8);

      if (!((fw >> kt) & 1u)) {  // key padding mask (raw-domain additive)
#pragma unroll
        for (int m = 0; m < 4; ++m) {
          float4 mv = *reinterpret_cast<const float4*>(gm + b * TT + kv0 + m * 16 + g * 4);
#pragma unroll
          for (int n = 0; n < 2; ++n) {
            s[m][n][0] += mv.x; s[m][n][1] += mv.y;
            s[m][n][2] += mv.z; s[m][n][3] += mv.w;
          }
        }
      }
      if (kt == nkt - 1) {  // causal predicate (diagonal tile only)
#pragma unroll
        for (int n = 0; n < 2; ++n) {
          const int q = q0 + n * 16 + lq;
#pragma unroll
          for (int m = 0; m < 4; ++m)
#pragma unroll
            for (int r = 0; r < 4; ++r) {
              int kv = kv0 + m * 16 + g * 4 + r;
              s[m][n][r] = (kv <= q) ? s[m][n][r] : -1e30f;
            }
        }
      }

      // online softmax per q-col, log2 domain, gated defer-rescale (THR=8)
#pragma unroll
      for (int n = 0; n < 2; ++n) {
        float rm = fmaxf(fmaxf(fmaxf(s[0][n][0], s[0][n][1]), fmaxf(s[0][n][2], s[0][n][3])),
                         fmaxf(fmaxf(s[1][n][0], s[1][n][1]), fmaxf(s[1][n][2], s[1][n][3])));
        float rm2 = fmaxf(fmaxf(fmaxf(s[2][n][0], s[2][n][1]), fmaxf(s[2][n][2], s[2][n][3])),
                          fmaxf(fmaxf(s[3][n][0], s[3][n][1]), fmaxf(s[3][n][2], s[3][n][3])));
        float rms = fmaxf(rm, rm2) * cs;  // per-lane, scaled log2 domain
        if (!__all(rms <= mrun[n] + 8.f)) {
          float rg = rms;
          rg = fmaxf(rg, __shfl_xor(rg, 16));
          rg = fmaxf(rg, __shfl_xor(rg, 32));
          float mnew = fmaxf(mrun[n], rg);
          float corr = __builtin_exp2f(mrun[n] - mnew);
          mrun[n] = mnew;
          lrun[n] *= corr;
#pragma unroll
          for (int nd = 0; nd < 4; ++nd)
#pragma unroll
            for (int r = 0; r < 4; ++r) o[nd][n][r] *= corr;
        }
        const float mneg = -mrun[n];
        float rs = 0.f;
#pragma unroll
        for (int m = 0; m < 4; ++m) {
          float p0 = __builtin_exp2f(fmaf(s[m][n][0], cs, mneg));
          float p1 = __builtin_exp2f(fmaf(s[m][n][1], cs, mneg));
          float p2 = __builtin_exp2f(fmaf(s[m][n][2], cs, mneg));
          float p3 = __builtin_exp2f(fmaf(s[m][n][3], cs, mneg));
          rs += (p0 + p1) + (p2 + p3);
          uint2 pw;
          pw.x = pkbf(p0, p1);
          pw.y = pkbf(p2, p3);
          *reinterpret_cast<uint2*>(Pw + (n * 16 + lq) * 72 + m * 16 + g * 4) = pw;
        }
        lrun[n] += rs;
      }

      asm volatile("s_waitcnt lgkmcnt(0)" ::: "memory");  // P visible wave-wide

      // O^T += V^T * P^T
      __builtin_amdgcn_s_setprio(1);
#pragma unroll
      for (int ks = 0; ks < 2; ++ks) {
        bf16x8 pf[2];
#pragma unroll
        for (int n = 0; n < 2; ++n)
          pf[n] = *reinterpret_cast<const bf16x8*>(Pw + (n * 16 + lq) * 72 + ks * 32 + g * 8);
#pragma unroll
        for (int nd = 0; nd < 4; ++nd) {
          o[nd][0] = __builtin_amdgcn_mfma_f32_16x16x32_bf16(vf[ks][nd], pf[0], o[nd][0], 0, 0, 0);
          o[nd][1] = __builtin_amdgcn_mfma_f32_16x16x32_bf16(vf[ks][nd], pf[1], o[nd][1], 0, 0, 0);
        }
      }
      __builtin_amdgcn_s_setprio(0);
    }

    // ---- merge kv-parity partials (lane-wise; same lane = same (q,d) coords) ----
    if (par) {
      float* row = &Mg[slotL][lane][0];
#pragma unroll
      for (int n = 0; n < 2; ++n)
#pragma unroll
        for (int nd = 0; nd < 4; ++nd)
          *reinterpret_cast<f32x4*>(row + (n * 4 + nd) * 4) = o[nd][n];
      row[32] = mrun[0]; row[33] = mrun[1];
      row[34] = lrun[0]; row[35] = lrun[1];
    }
    __syncthreads();
    if (!par) {
      const float* row = &Mg[slotL][lane][0];
      float mB[2] = {row[32], row[33]};
      float lB[2] = {row[34], row[35]};
#pragma unroll
      for (int n = 0; n < 2; ++n) {
        float ms = fmaxf(mrun[n], mB[n]);
        float cA = __builtin_exp2f(mrun[n] - ms);
        float cB = __builtin_exp2f(mB[n] - ms);
        float l = lrun[n] * cA + lB[n] * cB;
        l += __shfl_xor(l, 16);
        l += __shfl_xor(l, 32);
        float inv = 1.0f / l;
        const int q = q0 + n * 16 + lq;
#pragma unroll
        for (int nd = 0; nd < 4; ++nd) {
          f32x4 ob = *reinterpret_cast<const f32x4*>(row + (n * 4 + nd) * 4);
          u16x4 yv;
#pragma unroll
          for (int r = 0; r < 4; ++r)
            yv[r] = bfc((o[nd][n][r] * cA + ob[r] * cB) * inv);
          *reinterpret_cast<u16x4*>(
              Y + ((size_t)(b * TT + q)) * CC + h * DD + nd * 16 + g * 4) = yv;
        }
      }
    }
    __syncthreads();  // Mg reused next phase
  }
}

extern "C" void kernel_launch(void* const* d_in, const int* in_sizes, int n_in,
                              void* d_out, int out_size, void* d_ws, size_t ws_size,
                              hipStream_t stream) {
  const float* x  = (const float*)d_in[0];
  const int*   am = (const int*)d_in[1];
  const float* Wq = (const float*)d_in[2];
  const float* bq = (const float*)d_in[3];
  const float* Wk = (const float*)d_in[4];
  const float* bk = (const float*)d_in[5];
  const float* Wv = (const float*)d_in[6];
  const float* bv = (const float*)d_in[7];
  const float* Wp = (const float*)d_in[8];
  const float* bp = (const float*)d_in[9];
  float* out = (float*)d_out;

  char* ws = (char*)d_ws;
  u16* xb    = (u16*)(ws);                        // 16 MB  [8192][1024] bf16
  u16* wqkvT = (u16*)(ws + (16ull << 20));        //  6 MB  [3072][1024] bf16 (W^T)
  u16* wpT   = (u16*)(ws + (22ull << 20));        //  2 MB  [1024][1024] bf16 (Wp^T)
  u16* qw    = (u16*)(ws + (24ull << 20));        // 16 MB  [B,H,T,D] bf16
  u16* kw    = (u16*)(ws + (40ull << 20));        // 16 MB  [B,H,T,D] bf16
  u16* vw    = (u16*)(ws + (56ull << 20));        // 16 MB  [B,H,D,T] bf16 (transposed!)
  u16* yb    = (u16*)(ws + (72ull << 20));        // 16 MB  [B,T,C] bf16
  // mask scratch lives in d_out (dead until final proj GEMM overwrites it)
  float* gm  = (float*)d_out;                     // 32 KB [B][T] additive mask
  u32* fwords = (u32*)((char*)d_out + (64ull << 10));  // [B] chunk-valid bitmask

  mask_prep_kernel<<<dim3(BB), 256, 0, stream>>>(am, gm, fwords);
  {
    int n8 = BB * TT * CC / 8;
    cvt_bf16_kernel<<<n8 / 256, 256, 0, stream>>>(x, xb, n8);
  }
  transp_w_kernel<<<dim3(32, 32, 4), 256, 0, stream>>>(Wq, Wk, Wv, Wp, wqkvT, wpT);
  gemm_bt_kernel<0><<<dim3(64, 24), 256, 0, stream>>>(
      xb, wqkvT, CC, 3 * CC, bq, bk, bv, qw, kw, vw, nullptr);
  attn_kernel<<<dim3(1024), 256, 0, stream>>>(qw, kw, vw, gm, fwords, yb);
  gemm_bt_kernel<1><<<dim3(64, 8), 256, 0, stream>>>(
      yb, wpT, CC, CC, bp, nullptr, nullptr, nullptr, nullptr, nullptr, out);
}

// Round 7
// 248.062 us; speedup vs baseline: 1.2769x; 1.2769x over previous
//
#include <hip/hip_runtime.h>

#define BB 4
#define TT 2048
#define CC 1024
#define HH 16
#define DD 64

typedef unsigned short u16;
typedef unsigned int u32;
typedef __bf16 bf16;
typedef __attribute__((ext_vector_type(8))) bf16 bf16x8;
typedef __attribute__((ext_vector_type(8))) u16 u16x8;
typedef __attribute__((ext_vector_type(4))) u16 u16x4;
typedef __attribute__((ext_vector_type(4))) float f32x4;

static __device__ __forceinline__ u16 f2b(float f) {
  unsigned u = __builtin_bit_cast(unsigned, f);
  u += 0x7fffu + ((u >> 16) & 1u);
  return (u16)(u >> 16);
}
static __device__ __forceinline__ u16 bfc(float f) {
  return __builtin_bit_cast(u16, (__bf16)f);
}
static __device__ __forceinline__ u32 pkbf(float a, float b) {
  return (u32)bfc(a) | ((u32)bfc(b) << 16);
}

// ---------------- fp32 -> bf16 bulk convert (8 elems/thread) ----------------
__global__ void cvt_bf16_kernel(const float* __restrict__ src, u16* __restrict__ dst, int n8) {
  int i = blockIdx.x * blockDim.x + threadIdx.x;
  if (i >= n8) return;
  const float4* p4 = reinterpret_cast<const float4*>(src) + (size_t)i * 2;
  float4 a = p4[0], b = p4[1];
  u16x8 o;
  o[0] = f2b(a.x); o[1] = f2b(a.y); o[2] = f2b(a.z); o[3] = f2b(a.w);
  o[4] = f2b(b.x); o[5] = f2b(b.y); o[6] = f2b(b.z); o[7] = f2b(b.w);
  *reinterpret_cast<u16x8*>(dst + (size_t)i * 8) = o;
}

// ------------- W[k][n] fp32  ->  Wt[n][k] bf16  (32x32 LDS tile) -------------
__global__ void transp_w_kernel(const float* __restrict__ w0, const float* __restrict__ w1,
                                const float* __restrict__ w2, const float* __restrict__ w3,
                                u16* __restrict__ wqkvT, u16* __restrict__ wpT) {
  __shared__ float t[32][33];
  int z = blockIdx.z;
  const float* src = z == 0 ? w0 : z == 1 ? w1 : z == 2 ? w2 : w3;
  u16* dst = z < 3 ? wqkvT + (size_t)z * CC * CC : wpT;
  int k0 = blockIdx.x * 32, n0 = blockIdx.y * 32;
  int tx = threadIdx.x & 31, ty = threadIdx.x >> 5;
#pragma unroll
  for (int i = 0; i < 4; ++i)
    t[ty + i * 8][tx] = src[(size_t)(k0 + ty + i * 8) * CC + n0 + tx];
  __syncthreads();
#pragma unroll
  for (int i = 0; i < 4; ++i)
    dst[(size_t)(n0 + ty + i * 8) * CC + k0 + tx] = f2b(t[tx][ty + i * 8]);
}

// --------- mask prep: gm[b][t] = 0 / -1e30; fwords[b] bit kt = chunk-all-valid ---------
__global__ void mask_prep_kernel(const int* __restrict__ am, float* __restrict__ gm,
                                 u32* __restrict__ fwords) {
  __shared__ u32 sf[32];
  int b = blockIdx.x;
  int lane = threadIdx.x & 63, w = threadIdx.x >> 6;
#pragma unroll
  for (int j = 0; j < 8; ++j) {
    int c = w * 8 + j;
    int i = c * 64 + lane;
    int v = am[b * TT + i];
    gm[b * TT + i] = v ? 0.f : -1e30f;
    unsigned long long bal = __ballot(v != 0);
    if (lane == 0) sf[c] = (bal == ~0ull) ? 1u : 0u;
  }
  __syncthreads();
  if (threadIdx.x == 0) {
    u32 fw = 0;
    for (int c = 0; c < 32; ++c) fw |= sf[c] << c;
    fwords[b] = fw;
  }
}

// ---------------- bf16 GEMM: C[m][n] = sum_k A[m][k]*Bt[n][k] ----------------
// 128x128 tile, BK=32, 4 waves, 16x16x32 MFMA, global_load_lds.
// MODE 0: QKV epilogue -> Q,K scatter to [B,H,T,D]; V to [B,H,D,T] (transposed)
// MODE 1: fp32 out[m*N+n] = acc + bias[n]
template <int MODE>
__global__ __launch_bounds__(256) void gemm_bt_kernel(
    const u16* __restrict__ A, const u16* __restrict__ Bt, int K, int N,
    const float* __restrict__ b0, const float* __restrict__ b1, const float* __restrict__ b2,
    u16* __restrict__ q_out, u16* __restrict__ k_out, u16* __restrict__ v_out,
    float* __restrict__ f_out) {
  __shared__ u16 As[128 * 32];
  __shared__ u16 Bs[128 * 32];
  const int tid = threadIdx.x, lane = tid & 63, w = tid >> 6;
  const int wm = w >> 1, wn = w & 1;
  const int m0 = blockIdx.x * 128, n0 = blockIdx.y * 128;
  const int lrow = lane >> 2, lcol = (lane & 3) * 8;
  f32x4 acc[4][4] = {};

  for (int k0 = 0; k0 < K; k0 += 32) {
    if (k0) __syncthreads();
#pragma unroll
    for (int r = 0; r < 2; ++r) {
      int row = r * 64 + w * 16 + lrow;
      __builtin_amdgcn_global_load_lds(
          (const __attribute__((address_space(1))) void*)(A + (size_t)(m0 + row) * K + k0 + lcol),
          (__attribute__((address_space(3))) void*)(As + (r * 64 + w * 16) * 32),
          16, 0, 0);
      __builtin_amdgcn_global_load_lds(
          (const __attribute__((address_space(1))) void*)(Bt + (size_t)(n0 + row) * K + k0 + lcol),
          (__attribute__((address_space(3))) void*)(Bs + (r * 64 + w * 16) * 32),
          16, 0, 0);
    }
    __syncthreads();
    bf16x8 af[4], bfr[4];
#pragma unroll
    for (int i = 0; i < 4; ++i) {
      af[i] = *reinterpret_cast<const bf16x8*>(&As[(wm * 64 + i * 16 + (lane & 15)) * 32 + (lane >> 4) * 8]);
      bfr[i] = *reinterpret_cast<const bf16x8*>(&Bs[(wn * 64 + i * 16 + (lane & 15)) * 32 + (lane >> 4) * 8]);
    }
#pragma unroll
    for (int i = 0; i < 4; ++i)
#pragma unroll
      for (int j = 0; j < 4; ++j)
        acc[i][j] = __builtin_amdgcn_mfma_f32_16x16x32_bf16(af[i], bfr[j], acc[i][j], 0, 0, 0);
  }

  const int mrow = m0 + wm * 64;
  const int ncol = n0 + wn * 64;
  if (MODE == 0) {
    const int g = n0 >> 10;  // 0:Q 1:K 2:V (uniform per block)
    const float* bias = g == 0 ? b0 : g == 1 ? b1 : b2;
    if (g < 2) {
      u16* dst = g == 0 ? q_out : k_out;
#pragma unroll
      for (int i = 0; i < 4; ++i)
#pragma unroll
        for (int j = 0; j < 4; ++j)
#pragma unroll
          for (int r = 0; r < 4; ++r) {
            int m = mrow + i * 16 + (lane >> 4) * 4 + r;
            int n = ncol + j * 16 + (lane & 15);
            float v = acc[i][j][r] + bias[n & 1023];
            int b = m >> 11, t = m & 2047;
            int h = (n >> 6) & 15, d = n & 63;
            dst[(((size_t)(b * HH + h)) * TT + t) * DD + d] = f2b(v);
          }
    } else {
      // V transposed: [B,H,D,T]; 4 consecutive t per lane -> 8B store
#pragma unroll
      for (int i = 0; i < 4; ++i)
#pragma unroll
        for (int j = 0; j < 4; ++j) {
          int n = ncol + j * 16 + (lane & 15);
          int h = (n >> 6) & 15, d = n & 63;
          float bias_v = bias[n & 1023];
          int mb = mrow + i * 16 + (lane >> 4) * 4;
          int b = mb >> 11, t = mb & 2047;
          u16x4 vv;
#pragma unroll
          for (int r = 0; r < 4; ++r) vv[r] = f2b(acc[i][j][r] + bias_v);
          *reinterpret_cast<u16x4*>(v_out + (((size_t)(b * HH + h)) * DD + d) * TT + t) = vv;
        }
    }
  } else {
#pragma unroll
    for (int i = 0; i < 4; ++i)
#pragma unroll
      for (int j = 0; j < 4; ++j)
#pragma unroll
        for (int r = 0; r < 4; ++r) {
          int m = mrow + i * 16 + (lane >> 4) * 4 + r;
          int n = ncol + j * 16 + (lane & 15);
          f_out[(size_t)m * N + n] = acc[i][j][r] + b0[n];
        }
  }
}

// ------------- causal flash attention: swapped operands + split-kv wave pairs -------------
// S^T = mfma(K,Q), O^T = mfma(V^T,P^T). Each pair-slot (q-tiles iw & 63-iw) is handled
// by TWO waves interleaving kv tiles (even/odd) -> 4096 waves = 4/SIMD for latency
// hiding. Partials (o,m,l) merged lane-wise through LDS once per phase.
// NOTE: (256,2) bound, NOT (256,4): r6's (256,4) made the allocator pick 64 VGPR for a
// ~100-reg live set -> 570 MB of scratch spill traffic. 128 VGPR still gives 4 blk/CU.
__global__ __launch_bounds__(256, 2) void attn_kernel(
    const u16* __restrict__ Q, const u16* __restrict__ K, const u16* __restrict__ Vt,
    const float* __restrict__ gm, const u32* __restrict__ fwords, u16* __restrict__ Y) {
  __shared__ u16 Pls[4][32 * 72];     // per-wave P buffer [32 q][64 kv], stride 72
  __shared__ float Mg[2][64][37];     // per-slot merge buffer [lane][32 o + m0 m1 l0 l1]
  const int flat = blockIdx.x;
  const int xcd = flat & 7, idx = flat >> 3;  // idx 0..127
  const int bh = xcd * 8 + (idx & 7);         // 8 heads per XCD (K/V L2 residency)
  const int jb = idx >> 3;                    // 0..15 block-slot within head
  const int b = bh >> 4, h = bh & 15;
  const int lane = threadIdx.x & 63, w = threadIdx.x >> 6;
  const int slotL = w >> 1;   // local slot 0,1
  const int par = w & 1;      // kv tile parity for this wave
  const int iw = jb * 2 + slotL;  // global pair-slot 0..31
  const int lq = lane & 15, g = lane >> 4;
  const u16* Qb = Q + (size_t)bh * TT * DD;
  const u16* Kb = K + (size_t)bh * TT * DD;
  const u16* Vb = Vt + (size_t)bh * DD * TT;
  u16* Pw = &Pls[w][0];
  const u32 fw = fwords[b];
  const float cs = 0.125f * 1.44269504089f;  // scale * log2(e)

  for (int phase = 0; phase < 2; ++phase) {
    const int qt = phase == 0 ? iw : 63 - iw;
    const int q0 = qt * 32;
    const int nkt = (qt >> 1) + 1;  // equal for both slots in this block (qt pair 2j,2j+1)

    bf16x8 qf[2][2];
#pragma unroll
    for (int n = 0; n < 2; ++n)
#pragma unroll
      for (int ks = 0; ks < 2; ++ks)
        qf[n][ks] = *reinterpret_cast<const bf16x8*>(
            Qb + (size_t)(q0 + n * 16 + lq) * DD + ks * 32 + g * 8);

    f32x4 o[4][2] = {};  // O^T: row d = nd*16+4g+r, col q = n*16+lq
    float mrun[2] = {-1e30f, -1e30f};
    float lrun[2] = {0.f, 0.f};  // per-lane partial (this lane's 16 kv)

    for (int kt = par; kt < nkt; kt += 2) {
      const int kv0 = kt * 64;
      bf16x8 kf[4][2];
#pragma unroll
      for (int m = 0; m < 4; ++m)
#pragma unroll
        for (int ks = 0; ks < 2; ++ks)
          kf[m][ks] = *reinterpret_cast<const bf16x8*>(
              Kb + (size_t)(kv0 + m * 16 + lq) * DD + ks * 32 + g * 8);

      f32x4 s[4][2] = {};
      __builtin_amdgcn_s_setprio(1);
#pragma unroll
      for (int m = 0; m < 4; ++m)
#pragma unroll
        for (int ks = 0; ks < 2; ++ks)
#pragma unroll
          for (int n = 0; n < 2; ++n)
            s[m][n] = __builtin_amdgcn_mfma_f32_16x16x32_bf16(kf[m][ks], qf[n][ks], s[m][n], 0, 0, 0);
      __builtin_amdgcn_s_setprio(0);

      // V^T fragments issued early: consumed only after softmax
      bf16x8 vf[2][4];
#pragma unroll
      for (int ks = 0; ks < 2; ++ks)
#pragma unroll
        for (int nd = 0; nd < 4; ++nd)
          vf[ks][nd] = *reinterpret_cast<const bf16x8*>(
              Vb + (size_t)(nd * 16 + lq) * TT + kv0 + ks * 32 + g * 8);

      if (!((fw >> kt) & 1u)) {  // key padding mask (raw-domain additive)
#pragma unroll
        for (int m = 0; m < 4; ++m) {
          float4 mv = *reinterpret_cast<const float4*>(gm + b * TT + kv0 + m * 16 + g * 4);
#pragma unroll
          for (int n = 0; n < 2; ++n) {
            s[m][n][0] += mv.x; s[m][n][1] += mv.y;
            s[m][n][2] += mv.z; s[m][n][3] += mv.w;
          }
        }
      }
      if (kt == nkt - 1) {  // causal predicate (diagonal tile only)
#pragma unroll
        for (int n = 0; n < 2; ++n) {
          const int q = q0 + n * 16 + lq;
#pragma unroll
          for (int m = 0; m < 4; ++m)
#pragma unroll
            for (int r = 0; r < 4; ++r) {
              int kv = kv0 + m * 16 + g * 4 + r;
              s[m][n][r] = (kv <= q) ? s[m][n][r] : -1e30f;
            }
        }
      }

      // online softmax per q-col, log2 domain, gated defer-rescale (THR=8)
#pragma unroll
      for (int n = 0; n < 2; ++n) {
        float rm = fmaxf(fmaxf(fmaxf(s[0][n][0], s[0][n][1]), fmaxf(s[0][n][2], s[0][n][3])),
                         fmaxf(fmaxf(s[1][n][0], s[1][n][1]), fmaxf(s[1][n][2], s[1][n][3])));
        float rm2 = fmaxf(fmaxf(fmaxf(s[2][n][0], s[2][n][1]), fmaxf(s[2][n][2], s[2][n][3])),
                          fmaxf(fmaxf(s[3][n][0], s[3][n][1]), fmaxf(s[3][n][2], s[3][n][3])));
        float rms = fmaxf(rm, rm2) * cs;  // per-lane, scaled log2 domain
        if (!__all(rms <= mrun[n] + 8.f)) {
          float rg = rms;
          rg = fmaxf(rg, __shfl_xor(rg, 16));
          rg = fmaxf(rg, __shfl_xor(rg, 32));
          float mnew = fmaxf(mrun[n], rg);
          float corr = __builtin_exp2f(mrun[n] - mnew);
          mrun[n] = mnew;
          lrun[n] *= corr;
#pragma unroll
          for (int nd = 0; nd < 4; ++nd)
#pragma unroll
            for (int r = 0; r < 4; ++r) o[nd][n][r] *= corr;
        }
        const float mneg = -mrun[n];
        float rs = 0.f;
#pragma unroll
        for (int m = 0; m < 4; ++m) {
          float p0 = __builtin_exp2f(fmaf(s[m][n][0], cs, mneg));
          float p1 = __builtin_exp2f(fmaf(s[m][n][1], cs, mneg));
          float p2 = __builtin_exp2f(fmaf(s[m][n][2], cs, mneg));
          float p3 = __builtin_exp2f(fmaf(s[m][n][3], cs, mneg));
          rs += (p0 + p1) + (p2 + p3);
          uint2 pw;
          pw.x = pkbf(p0, p1);
          pw.y = pkbf(p2, p3);
          *reinterpret_cast<uint2*>(Pw + (n * 16 + lq) * 72 + m * 16 + g * 4) = pw;
        }
        lrun[n] += rs;
      }

      asm volatile("s_waitcnt lgkmcnt(0)" ::: "memory");  // P visible wave-wide

      // O^T += V^T * P^T
      __builtin_amdgcn_s_setprio(1);
#pragma unroll
      for (int ks = 0; ks < 2; ++ks) {
        bf16x8 pf[2];
#pragma unroll
        for (int n = 0; n < 2; ++n)
          pf[n] = *reinterpret_cast<const bf16x8*>(Pw + (n * 16 + lq) * 72 + ks * 32 + g * 8);
#pragma unroll
        for (int nd = 0; nd < 4; ++nd) {
          o[nd][0] = __builtin_amdgcn_mfma_f32_16x16x32_bf16(vf[ks][nd], pf[0], o[nd][0], 0, 0, 0);
          o[nd][1] = __builtin_amdgcn_mfma_f32_16x16x32_bf16(vf[ks][nd], pf[1], o[nd][1], 0, 0, 0);
        }
      }
      __builtin_amdgcn_s_setprio(0);
    }

    // ---- merge kv-parity partials (lane-wise; same lane = same (q,d) coords) ----
    if (par) {
      float* row = &Mg[slotL][lane][0];
#pragma unroll
      for (int n = 0; n < 2; ++n)
#pragma unroll
        for (int nd = 0; nd < 4; ++nd)
          *reinterpret_cast<f32x4*>(row + (n * 4 + nd) * 4) = o[nd][n];
      row[32] = mrun[0]; row[33] = mrun[1];
      row[34] = lrun[0]; row[35] = lrun[1];
    }
    __syncthreads();
    if (!par) {
      const float* row = &Mg[slotL][lane][0];
      float mB[2] = {row[32], row[33]};
      float lB[2] = {row[34], row[35]};
#pragma unroll
      for (int n = 0; n < 2; ++n) {
        float ms = fmaxf(mrun[n], mB[n]);
        float cA = __builtin_exp2f(mrun[n] - ms);
        float cB = __builtin_exp2f(mB[n] - ms);
        float l = lrun[n] * cA + lB[n] * cB;
        l += __shfl_xor(l, 16);
        l += __shfl_xor(l, 32);
        float inv = 1.0f / l;
        const int q = q0 + n * 16 + lq;
#pragma unroll
        for (int nd = 0; nd < 4; ++nd) {
          f32x4 ob = *reinterpret_cast<const f32x4*>(row + (n * 4 + nd) * 4);
          u16x4 yv;
#pragma unroll
          for (int r = 0; r < 4; ++r)
            yv[r] = bfc((o[nd][n][r] * cA + ob[r] * cB) * inv);
          *reinterpret_cast<u16x4*>(
              Y + ((size_t)(b * TT + q)) * CC + h * DD + nd * 16 + g * 4) = yv;
        }
      }
    }
    __syncthreads();  // Mg reused next phase
  }
}

extern "C" void kernel_launch(void* const* d_in, const int* in_sizes, int n_in,
                              void* d_out, int out_size, void* d_ws, size_t ws_size,
                              hipStream_t stream) {
  const float* x  = (const float*)d_in[0];
  const int*   am = (const int*)d_in[1];
  const float* Wq = (const float*)d_in[2];
  const float* bq = (const float*)d_in[3];
  const float* Wk = (const float*)d_in[4];
  const float* bk = (const float*)d_in[5];
  const float* Wv = (const float*)d_in[6];
  const float* bv = (const float*)d_in[7];
  const float* Wp = (const float*)d_in[8];
  const float* bp = (const float*)d_in[9];
  float* out = (float*)d_out;

  char* ws = (char*)d_ws;
  u16* xb    = (u16*)(ws);                        // 16 MB  [8192][1024] bf16
  u16* wqkvT = (u16*)(ws + (16ull << 20));        //  6 MB  [3072][1024] bf16 (W^T)
  u16* wpT   = (u16*)(ws + (22ull << 20));        //  2 MB  [1024][1024] bf16 (Wp^T)
  u16* qw    = (u16*)(ws + (24ull << 20));        // 16 MB  [B,H,T,D] bf16
  u16* kw    = (u16*)(ws + (40ull << 20));        // 16 MB  [B,H,T,D] bf16
  u16* vw    = (u16*)(ws + (56ull << 20));        // 16 MB  [B,H,D,T] bf16 (transposed!)
  u16* yb    = (u16*)(ws + (72ull << 20));        // 16 MB  [B,T,C] bf16
  // mask scratch lives in d_out (dead until final proj GEMM overwrites it)
  float* gm  = (float*)d_out;                     // 32 KB [B][T] additive mask
  u32* fwords = (u32*)((char*)d_out + (64ull << 10));  // [B] chunk-valid bitmask

  mask_prep_kernel<<<dim3(BB), 256, 0, stream>>>(am, gm, fwords);
  {
    int n8 = BB * TT * CC / 8;
    cvt_bf16_kernel<<<n8 / 256, 256, 0, stream>>>(x, xb, n8);
  }
  transp_w_kernel<<<dim3(32, 32, 4), 256, 0, stream>>>(Wq, Wk, Wv, Wp, wqkvT, wpT);
  gemm_bt_kernel<0><<<dim3(64, 24), 256, 0, stream>>>(
      xb, wqkvT, CC, 3 * CC, bq, bk, bv, qw, kw, vw, nullptr);
  attn_kernel<<<dim3(1024), 256, 0, stream>>>(qw, kw, vw, gm, fwords, yb);
  gemm_bt_kernel<1><<<dim3(64, 8), 256, 0, stream>>>(
      yb, wpT, CC, CC, bp, nullptr, nullptr, nullptr, nullptr, nullptr, out);
}

// Round 8
// 193.228 us; speedup vs baseline: 1.6393x; 1.2838x over previous
//
#include <hip/hip_runtime.h>

#define BB 4
#define TT 2048
#define CC 1024
#define HH 16
#define DD 64

typedef unsigned short u16;
typedef unsigned int u32;
typedef __bf16 bf16;
typedef __attribute__((ext_vector_type(8))) bf16 bf16x8;
typedef __attribute__((ext_vector_type(8))) u16 u16x8;
typedef __attribute__((ext_vector_type(4))) u16 u16x4;
typedef __attribute__((ext_vector_type(4))) float f32x4;

static __device__ __forceinline__ u16 f2b(float f) {
  unsigned u = __builtin_bit_cast(unsigned, f);
  u += 0x7fffu + ((u >> 16) & 1u);
  return (u16)(u >> 16);
}
static __device__ __forceinline__ u16 bfc(float f) {
  return __builtin_bit_cast(u16, (__bf16)f);
}

// ---------------- fp32 -> bf16 bulk convert (8 elems/thread) ----------------
__global__ void cvt_bf16_kernel(const float* __restrict__ src, u16* __restrict__ dst, int n8) {
  int i = blockIdx.x * blockDim.x + threadIdx.x;
  if (i >= n8) return;
  const float4* p4 = reinterpret_cast<const float4*>(src) + (size_t)i * 2;
  float4 a = p4[0], b = p4[1];
  u16x8 o;
  o[0] = f2b(a.x); o[1] = f2b(a.y); o[2] = f2b(a.z); o[3] = f2b(a.w);
  o[4] = f2b(b.x); o[5] = f2b(b.y); o[6] = f2b(b.z); o[7] = f2b(b.w);
  *reinterpret_cast<u16x8*>(dst + (size_t)i * 8) = o;
}

// ------------- W[k][n] fp32  ->  Wt[n][k] bf16  (32x32 LDS tile) -------------
__global__ void transp_w_kernel(const float* __restrict__ w0, const float* __restrict__ w1,
                                const float* __restrict__ w2, const float* __restrict__ w3,
                                u16* __restrict__ wqkvT, u16* __restrict__ wpT) {
  __shared__ float t[32][33];
  int z = blockIdx.z;
  const float* src = z == 0 ? w0 : z == 1 ? w1 : z == 2 ? w2 : w3;
  u16* dst = z < 3 ? wqkvT + (size_t)z * CC * CC : wpT;
  int k0 = blockIdx.x * 32, n0 = blockIdx.y * 32;
  int tx = threadIdx.x & 31, ty = threadIdx.x >> 5;
#pragma unroll
  for (int i = 0; i < 4; ++i)
    t[ty + i * 8][tx] = src[(size_t)(k0 + ty + i * 8) * CC + n0 + tx];
  __syncthreads();
#pragma unroll
  for (int i = 0; i < 4; ++i)
    dst[(size_t)(n0 + ty + i * 8) * CC + k0 + tx] = f2b(t[tx][ty + i * 8]);
}

// --------- mask prep: gm[b][t] = 0 / -1e30; fwords[b] bit kt = chunk-all-valid ---------
__global__ void mask_prep_kernel(const int* __restrict__ am, float* __restrict__ gm,
                                 u32* __restrict__ fwords) {
  __shared__ u32 sf[32];
  int b = blockIdx.x;
  int lane = threadIdx.x & 63, w = threadIdx.x >> 6;
#pragma unroll
  for (int j = 0; j < 8; ++j) {
    int c = w * 8 + j;
    int i = c * 64 + lane;
    int v = am[b * TT + i];
    gm[b * TT + i] = v ? 0.f : -1e30f;
    unsigned long long bal = __ballot(v != 0);
    if (lane == 0) sf[c] = (bal == ~0ull) ? 1u : 0u;
  }
  __syncthreads();
  if (threadIdx.x == 0) {
    u32 fw = 0;
    for (int c = 0; c < 32; ++c) fw |= sf[c] << c;
    fwords[b] = fw;
  }
}

// ---------------- bf16 GEMM: C[m][n] = sum_k A[m][k]*Bt[n][k] ----------------
// 128x128 tile, BK=32, 4 waves, 16x16x32 MFMA, global_load_lds.
// MODE 0: QKV epilogue -> Q (pre-scaled by 0.125*log2e) / K to [B,H,T,D]; V to [B,H,D,T]
// MODE 1: fp32 out[m*N+n] = acc + bias[n]
template <int MODE>
__global__ __launch_bounds__(256) void gemm_bt_kernel(
    const u16* __restrict__ A, const u16* __restrict__ Bt, int K, int N,
    const float* __restrict__ b0, const float* __restrict__ b1, const float* __restrict__ b2,
    u16* __restrict__ q_out, u16* __restrict__ k_out, u16* __restrict__ v_out,
    float* __restrict__ f_out) {
  __shared__ u16 As[128 * 32];
  __shared__ u16 Bs[128 * 32];
  const int tid = threadIdx.x, lane = tid & 63, w = tid >> 6;
  const int wm = w >> 1, wn = w & 1;
  const int m0 = blockIdx.x * 128, n0 = blockIdx.y * 128;
  const int lrow = lane >> 2, lcol = (lane & 3) * 8;
  f32x4 acc[4][4] = {};

  for (int k0 = 0; k0 < K; k0 += 32) {
    if (k0) __syncthreads();
#pragma unroll
    for (int r = 0; r < 2; ++r) {
      int row = r * 64 + w * 16 + lrow;
      __builtin_amdgcn_global_load_lds(
          (const __attribute__((address_space(1))) void*)(A + (size_t)(m0 + row) * K + k0 + lcol),
          (__attribute__((address_space(3))) void*)(As + (r * 64 + w * 16) * 32),
          16, 0, 0);
      __builtin_amdgcn_global_load_lds(
          (const __attribute__((address_space(1))) void*)(Bt + (size_t)(n0 + row) * K + k0 + lcol),
          (__attribute__((address_space(3))) void*)(Bs + (r * 64 + w * 16) * 32),
          16, 0, 0);
    }
    __syncthreads();
    bf16x8 af[4], bfr[4];
#pragma unroll
    for (int i = 0; i < 4; ++i) {
      af[i] = *reinterpret_cast<const bf16x8*>(&As[(wm * 64 + i * 16 + (lane & 15)) * 32 + (lane >> 4) * 8]);
      bfr[i] = *reinterpret_cast<const bf16x8*>(&Bs[(wn * 64 + i * 16 + (lane & 15)) * 32 + (lane >> 4) * 8]);
    }
#pragma unroll
    for (int i = 0; i < 4; ++i)
#pragma unroll
      for (int j = 0; j < 4; ++j)
        acc[i][j] = __builtin_amdgcn_mfma_f32_16x16x32_bf16(af[i], bfr[j], acc[i][j], 0, 0, 0);
  }

  const int mrow = m0 + wm * 64;
  const int ncol = n0 + wn * 64;
  if (MODE == 0) {
    const int g = n0 >> 10;  // 0:Q 1:K 2:V (uniform per block)
    const float* bias = g == 0 ? b0 : g == 1 ? b1 : b2;
    if (g < 2) {
      u16* dst = g == 0 ? q_out : k_out;
      const float scl = (g == 0) ? 0.18033688f : 1.0f;  // Q pre-scale: 0.125*log2(e)
#pragma unroll
      for (int i = 0; i < 4; ++i)
#pragma unroll
        for (int j = 0; j < 4; ++j)
#pragma unroll
          for (int r = 0; r < 4; ++r) {
            int m = mrow + i * 16 + (lane >> 4) * 4 + r;
            int n = ncol + j * 16 + (lane & 15);
            float v = (acc[i][j][r] + bias[n & 1023]) * scl;
            int b = m >> 11, t = m & 2047;
            int h = (n >> 6) & 15, d = n & 63;
            dst[(((size_t)(b * HH + h)) * TT + t) * DD + d] = f2b(v);
          }
    } else {
      // V transposed: [B,H,D,T]; 4 consecutive t per lane -> 8B store
#pragma unroll
      for (int i = 0; i < 4; ++i)
#pragma unroll
        for (int j = 0; j < 4; ++j) {
          int n = ncol + j * 16 + (lane & 15);
          int h = (n >> 6) & 15, d = n & 63;
          float bias_v = bias[n & 1023];
          int mb = mrow + i * 16 + (lane >> 4) * 4;
          int b = mb >> 11, t = mb & 2047;
          u16x4 vv;
#pragma unroll
          for (int r = 0; r < 4; ++r) vv[r] = f2b(acc[i][j][r] + bias_v);
          *reinterpret_cast<u16x4*>(v_out + (((size_t)(b * HH + h)) * DD + d) * TT + t) = vv;
        }
    }
  } else {
#pragma unroll
    for (int i = 0; i < 4; ++i)
#pragma unroll
      for (int j = 0; j < 4; ++j)
#pragma unroll
        for (int r = 0; r < 4; ++r) {
          int m = mrow + i * 16 + (lane >> 4) * 4 + r;
          int n = ncol + j * 16 + (lane & 15);
          f_out[(size_t)m * N + n] = acc[i][j][r] + b0[n];
        }
  }
}

// ------- causal flash attention: LDS-staged K/V double-buffer + counted vmcnt -------
// Block = 4 waves = q-tiles {4jb..4jb+3} of one head; K [64kv][64d] and V^T [64d][64kv]
// staged cooperatively via global_load_lds (XOR-swizzled: inverse-swz source + swz read),
// 2 tiles ahead, vmcnt(4) steady-state (never 0). S^T = mfma(K,Q), O^T = mfma(V^T,P^T).
// Q pre-scaled to log2 domain in GEMM. LPT: heavy blocks (jb high) dispatch first.
__global__ __launch_bounds__(256, 2) void attn_kernel(
    const u16* __restrict__ Q, const u16* __restrict__ K, const u16* __restrict__ Vt,
    const float* __restrict__ gm, const u32* __restrict__ fwords, u16* __restrict__ Y) {
  // LDS: K dbuf [2][8192B] @0 | V dbuf [2][8192B] @16384 | P [4 waves][32q x 72 u16] @32768
  __shared__ __align__(16) char LDS[51200];
  const int flat = blockIdx.x;
  const int xcd = flat & 7, idx = flat >> 3;
  const int bh = xcd * 8 + (idx & 7);  // 8 heads per XCD (K/V L2 residency)
  const int jb = 15 - (idx >> 3);      // heavy-first (LPT backfill)
  const int b = bh >> 4, h = bh & 15;
  const int tid = threadIdx.x, lane = tid & 63, w = tid >> 6;
  const int lq = lane & 15, g = lane >> 4;
  const int qt = 4 * jb + w;
  const int q0 = qt * 32;
  const int nkt = (qt >> 1) + 1;   // this wave's kv-tile count
  const int nktm = 2 * jb + 2;     // block max (always even, >= 2)
  const u32 fw = fwords[b];

  const u16* Qb = Q + (size_t)bh * TT * DD;
  const char* Kb = (const char*)(K + (size_t)bh * TT * DD);
  const char* Vb = (const char*)(Vt + (size_t)bh * DD * TT);

  // staging: per-lane global source, inverse-swizzled column (rule #21)
  const int l3 = lane >> 3, l7 = lane & 7;
  const int swb = (l7 * 16) ^ (l3 << 4);
  const char* kp0 = Kb + (2 * w + 0) * 1024 + l3 * 128 + swb;
  const char* kp1 = Kb + (2 * w + 1) * 1024 + l3 * 128 + swb;
  const char* vp0 = Vb + (size_t)((2 * w + 0) * 8 + l3) * 4096 + swb;
  const char* vp1 = Vb + (size_t)((2 * w + 1) * 8 + l3) * 4096 + swb;

  // fragment read bases (swizzled); imm offsets handle m/nd/ks/buf
  const int sw2 = (lq & 7) << 4;
  const int fb0 = lq * 128 + ((g * 16) ^ sw2);         // ks=0 (K and V share)
  const int fb1 = lq * 128 + (((64) + g * 16) ^ sw2);  // ks=1
  const int pwb = 32768 + w * 4608 + lq * 144 + g * 8;   // P write base
  const int prb = 32768 + w * 4608 + lq * 144 + g * 16;  // P read base

  auto STAGE = [&](int buf, int kt2) {
    const int ko = kt2 * 8192, vo = kt2 * 128, lb = buf * 8192;
    __builtin_amdgcn_global_load_lds(
        (const __attribute__((address_space(1))) void*)(kp0 + ko),
        (__attribute__((address_space(3))) void*)(LDS + lb + (2 * w + 0) * 1024), 16, 0, 0);
    __builtin_amdgcn_global_load_lds(
        (const __attribute__((address_space(1))) void*)(kp1 + ko),
        (__attribute__((address_space(3))) void*)(LDS + lb + (2 * w + 1) * 1024), 16, 0, 0);
    __builtin_amdgcn_global_load_lds(
        (const __attribute__((address_space(1))) void*)(vp0 + vo),
        (__attribute__((address_space(3))) void*)(LDS + 16384 + lb + (2 * w + 0) * 1024), 16, 0, 0);
    __builtin_amdgcn_global_load_lds(
        (const __attribute__((address_space(1))) void*)(vp1 + vo),
        (__attribute__((address_space(3))) void*)(LDS + 16384 + lb + (2 * w + 1) * 1024), 16, 0, 0);
  };

  bf16x8 qf[2][2];
#pragma unroll
  for (int n = 0; n < 2; ++n)
#pragma unroll
    for (int ks = 0; ks < 2; ++ks)
      qf[n][ks] = *reinterpret_cast<const bf16x8*>(
          Qb + (size_t)(q0 + n * 16 + lq) * DD + ks * 32 + g * 8);

  f32x4 o[4][2] = {};  // O^T: row d = nd*16+4g+r, col q = n*16+lq
  float mrun[2] = {-1e30f, -1e30f};
  float lrun[2] = {0.f, 0.f};  // per-lane partial; reduced once in epilogue
  const f32x4 z4 = {0.f, 0.f, 0.f, 0.f};

  STAGE(0, 0);
  STAGE(1, 1);

  auto TILE = [&](int BUF, int kt) {
    if (kt < nktm - 1)
      asm volatile("s_waitcnt vmcnt(4)" ::: "memory");
    else
      asm volatile("s_waitcnt vmcnt(0)" ::: "memory");
    asm volatile("s_barrier" ::: "memory");

    if (kt < nkt) {
      const int kv0 = kt * 64;
      // K fragments from swizzled LDS: 8 x ds_read_b128, imm offsets
      bf16x8 kf0[4], kf1[4];
#pragma unroll
      for (int m = 0; m < 4; ++m) {
        kf0[m] = *reinterpret_cast<const bf16x8*>(LDS + BUF * 8192 + m * 2048 + fb0);
        kf1[m] = *reinterpret_cast<const bf16x8*>(LDS + BUF * 8192 + m * 2048 + fb1);
      }
      f32x4 s[4][2];
      __builtin_amdgcn_s_setprio(1);
#pragma unroll
      for (int m = 0; m < 4; ++m)
#pragma unroll
        for (int n = 0; n < 2; ++n) {
          s[m][n] = __builtin_amdgcn_mfma_f32_16x16x32_bf16(kf0[m], qf[n][0], z4, 0, 0, 0);
          s[m][n] = __builtin_amdgcn_mfma_f32_16x16x32_bf16(kf1[m], qf[n][1], s[m][n], 0, 0, 0);
        }
      __builtin_amdgcn_s_setprio(0);

      if (!((fw >> kt) & 1u)) {  // key padding mask (log2-scaled domain: add scaled -inf ok)
#pragma unroll
        for (int m = 0; m < 4; ++m) {
          float4 mv = *reinterpret_cast<const float4*>(gm + b * TT + kv0 + m * 16 + g * 4);
#pragma unroll
          for (int n = 0; n < 2; ++n) {
            s[m][n][0] += mv.x; s[m][n][1] += mv.y;
            s[m][n][2] += mv.z; s[m][n][3] += mv.w;
          }
        }
      }
      if (kt == nkt - 1) {  // causal predicate (diagonal tile only)
#pragma unroll
        for (int n = 0; n < 2; ++n) {
          const int q = q0 + n * 16 + lq;
#pragma unroll
          for (int m = 0; m < 4; ++m)
#pragma unroll
            for (int r = 0; r < 4; ++r) {
              int kv = kv0 + m * 16 + g * 4 + r;
              s[m][n][r] = (kv <= q) ? s[m][n][r] : -1e30f;
            }
        }
      }

      // online softmax (s already in log2 domain), gated defer-rescale (THR=8)
#pragma unroll
      for (int n = 0; n < 2; ++n) {
        float rm = fmaxf(fmaxf(fmaxf(s[0][n][0], s[0][n][1]), fmaxf(s[0][n][2], s[0][n][3])),
                         fmaxf(fmaxf(s[1][n][0], s[1][n][1]), fmaxf(s[1][n][2], s[1][n][3])));
        float rm2 = fmaxf(fmaxf(fmaxf(s[2][n][0], s[2][n][1]), fmaxf(s[2][n][2], s[2][n][3])),
                          fmaxf(fmaxf(s[3][n][0], s[3][n][1]), fmaxf(s[3][n][2], s[3][n][3])));
        rm = fmaxf(rm, rm2);
        if (!__all(rm <= mrun[n] + 8.f)) {
          float rg = fmaxf(rm, __shfl_xor(rm, 16));
          rg = fmaxf(rg, __shfl_xor(rg, 32));
          float mnew = fmaxf(mrun[n], rg);
          float corr = __builtin_exp2f(mrun[n] - mnew);
          mrun[n] = mnew;
          lrun[n] *= corr;
#pragma unroll
          for (int nd = 0; nd < 4; ++nd)
#pragma unroll
            for (int r = 0; r < 4; ++r) o[nd][n][r] *= corr;
        }
        const float mn = mrun[n];
        float rs = 0.f;
#pragma unroll
        for (int m = 0; m < 4; ++m) {
          float p0 = __builtin_exp2f(s[m][n][0] - mn);
          float p1 = __builtin_exp2f(s[m][n][1] - mn);
          float p2 = __builtin_exp2f(s[m][n][2] - mn);
          float p3 = __builtin_exp2f(s[m][n][3] - mn);
          rs += (p0 + p1) + (p2 + p3);
          u32 wa, wb;
          asm("v_cvt_pk_bf16_f32 %0, %1, %2" : "=v"(wa) : "v"(p0), "v"(p1));
          asm("v_cvt_pk_bf16_f32 %0, %1, %2" : "=v"(wb) : "v"(p2), "v"(p3));
          uint2 pw; pw.x = wa; pw.y = wb;
          *reinterpret_cast<uint2*>(LDS + pwb + n * 2304 + m * 32) = pw;
        }
        lrun[n] += rs;
      }

      asm volatile("s_waitcnt lgkmcnt(0)" ::: "memory");  // P visible to own wave
      __builtin_amdgcn_sched_barrier(0);                  // rule #18

      // O^T += V^T * P^T  (V from swizzled LDS)
      __builtin_amdgcn_s_setprio(1);
#pragma unroll
      for (int ks = 0; ks < 2; ++ks) {
        const int fb = ks ? fb1 : fb0;
        bf16x8 pf0 = *reinterpret_cast<const bf16x8*>(LDS + prb + 0 * 2304 + ks * 64);
        bf16x8 pf1 = *reinterpret_cast<const bf16x8*>(LDS + prb + 1 * 2304 + ks * 64);
#pragma unroll
        for (int nd = 0; nd < 4; ++nd) {
          bf16x8 vf = *reinterpret_cast<const bf16x8*>(LDS + 16384 + BUF * 8192 + nd * 2048 + fb);
          o[nd][0] = __builtin_amdgcn_mfma_f32_16x16x32_bf16(vf, pf0, o[nd][0], 0, 0, 0);
          o[nd][1] = __builtin_amdgcn_mfma_f32_16x16x32_bf16(vf, pf1, o[nd][1], 0, 0, 0);
        }
      }
      __builtin_amdgcn_s_setprio(0);
    }

    asm volatile("s_barrier" ::: "memory");  // all waves done reading buf
    if (kt + 2 < nktm) STAGE(BUF, kt + 2);
  };

  for (int kt = 0; kt < nktm; kt += 2) {
    TILE(0, kt);
    TILE(1, kt + 1);
  }

  // epilogue: reduce per-lane lrun (2 shuffles, once), store Y packed 8B
#pragma unroll
  for (int n = 0; n < 2; ++n) {
    float l = lrun[n];
    l += __shfl_xor(l, 16);
    l += __shfl_xor(l, 32);
    float inv = 1.0f / l;
    const int q = q0 + n * 16 + lq;
#pragma unroll
    for (int nd = 0; nd < 4; ++nd) {
      u16x4 yv;
#pragma unroll
      for (int r = 0; r < 4; ++r) yv[r] = bfc(o[nd][n][r] * inv);
      *reinterpret_cast<u16x4*>(
          Y + ((size_t)(b * TT + q)) * CC + h * DD + nd * 16 + g * 4) = yv;
    }
  }
}

extern "C" void kernel_launch(void* const* d_in, const int* in_sizes, int n_in,
                              void* d_out, int out_size, void* d_ws, size_t ws_size,
                              hipStream_t stream) {
  const float* x  = (const float*)d_in[0];
  const int*   am = (const int*)d_in[1];
  const float* Wq = (const float*)d_in[2];
  const float* bq = (const float*)d_in[3];
  const float* Wk = (const float*)d_in[4];
  const float* bk = (const float*)d_in[5];
  const float* Wv = (const float*)d_in[6];
  const float* bv = (const float*)d_in[7];
  const float* Wp = (const float*)d_in[8];
  const float* bp = (const float*)d_in[9];
  float* out = (float*)d_out;

  char* ws = (char*)d_ws;
  u16* xb    = (u16*)(ws);                        // 16 MB  [8192][1024] bf16
  u16* wqkvT = (u16*)(ws + (16ull << 20));        //  6 MB  [3072][1024] bf16 (W^T)
  u16* wpT   = (u16*)(ws + (22ull << 20));        //  2 MB  [1024][1024] bf16 (Wp^T)
  u16* qw    = (u16*)(ws + (24ull << 20));        // 16 MB  [B,H,T,D] bf16 (pre-scaled)
  u16* kw    = (u16*)(ws + (40ull << 20));        // 16 MB  [B,H,T,D] bf16
  u16* vw    = (u16*)(ws + (56ull << 20));        // 16 MB  [B,H,D,T] bf16 (transposed!)
  u16* yb    = (u16*)(ws + (72ull << 20));        // 16 MB  [B,T,C] bf16
  // mask scratch lives in d_out (dead until final proj GEMM overwrites it)
  float* gm  = (float*)d_out;                     // 32 KB [B][T] additive mask
  u32* fwords = (u32*)((char*)d_out + (64ull << 10));  // [B] chunk-valid bitmask

  mask_prep_kernel<<<dim3(BB), 256, 0, stream>>>(am, gm, fwords);
  {
    int n8 = BB * TT * CC / 8;
    cvt_bf16_kernel<<<n8 / 256, 256, 0, stream>>>(x, xb, n8);
  }
  transp_w_kernel<<<dim3(32, 32, 4), 256, 0, stream>>>(Wq, Wk, Wv, Wp, wqkvT, wpT);
  gemm_bt_kernel<0><<<dim3(64, 24), 256, 0, stream>>>(
      xb, wqkvT, CC, 3 * CC, bq, bk, bv, qw, kw, vw, nullptr);
  attn_kernel<<<dim3(1024), 256, 0, stream>>>(qw, kw, vw, gm, fwords, yb);
  gemm_bt_kernel<1><<<dim3(64, 8), 256, 0, stream>>>(
      yb, wpT, CC, CC, bp, nullptr, nullptr, nullptr, nullptr, nullptr, out);
}

// Round 9
// 186.218 us; speedup vs baseline: 1.7010x; 1.0376x over previous
//
#include <hip/hip_runtime.h>

#define BB 4
#define TT 2048
#define CC 1024
#define HH 16
#define DD 64

typedef unsigned short u16;
typedef unsigned int u32;
typedef __bf16 bf16;
typedef __attribute__((ext_vector_type(8))) bf16 bf16x8;
typedef __attribute__((ext_vector_type(8))) u16 u16x8;
typedef __attribute__((ext_vector_type(4))) u16 u16x4;
typedef __attribute__((ext_vector_type(4))) float f32x4;

static __device__ __forceinline__ u16 f2b(float f) {
  unsigned u = __builtin_bit_cast(unsigned, f);
  u += 0x7fffu + ((u >> 16) & 1u);
  return (u16)(u >> 16);
}
static __device__ __forceinline__ u16 bfc(float f) {
  return __builtin_bit_cast(u16, (__bf16)f);
}

// ---------------- fp32 -> bf16 bulk convert (8 elems/thread) ----------------
__global__ void cvt_bf16_kernel(const float* __restrict__ src, u16* __restrict__ dst, int n8) {
  int i = blockIdx.x * blockDim.x + threadIdx.x;
  if (i >= n8) return;
  const float4* p4 = reinterpret_cast<const float4*>(src) + (size_t)i * 2;
  float4 a = p4[0], b = p4[1];
  u16x8 o;
  o[0] = f2b(a.x); o[1] = f2b(a.y); o[2] = f2b(a.z); o[3] = f2b(a.w);
  o[4] = f2b(b.x); o[5] = f2b(b.y); o[6] = f2b(b.z); o[7] = f2b(b.w);
  *reinterpret_cast<u16x8*>(dst + (size_t)i * 8) = o;
}

// ------------- W[k][n] fp32  ->  Wt[n][k] bf16  (32x32 LDS tile) -------------
__global__ void transp_w_kernel(const float* __restrict__ w0, const float* __restrict__ w1,
                                const float* __restrict__ w2, const float* __restrict__ w3,
                                u16* __restrict__ wqkvT, u16* __restrict__ wpT) {
  __shared__ float t[32][33];
  int z = blockIdx.z;
  const float* src = z == 0 ? w0 : z == 1 ? w1 : z == 2 ? w2 : w3;
  u16* dst = z < 3 ? wqkvT + (size_t)z * CC * CC : wpT;
  int k0 = blockIdx.x * 32, n0 = blockIdx.y * 32;
  int tx = threadIdx.x & 31, ty = threadIdx.x >> 5;
#pragma unroll
  for (int i = 0; i < 4; ++i)
    t[ty + i * 8][tx] = src[(size_t)(k0 + ty + i * 8) * CC + n0 + tx];
  __syncthreads();
#pragma unroll
  for (int i = 0; i < 4; ++i)
    dst[(size_t)(n0 + ty + i * 8) * CC + k0 + tx] = f2b(t[tx][ty + i * 8]);
}

// --------- mask prep: gm[b][t] = 0 / -1e30; fwords[b] bit kt = chunk-all-valid ---------
__global__ void mask_prep_kernel(const int* __restrict__ am, float* __restrict__ gm,
                                 u32* __restrict__ fwords) {
  __shared__ u32 sf[32];
  int b = blockIdx.x;
  int lane = threadIdx.x & 63, w = threadIdx.x >> 6;
#pragma unroll
  for (int j = 0; j < 8; ++j) {
    int c = w * 8 + j;
    int i = c * 64 + lane;
    int v = am[b * TT + i];
    gm[b * TT + i] = v ? 0.f : -1e30f;
    unsigned long long bal = __ballot(v != 0);
    if (lane == 0) sf[c] = (bal == ~0ull) ? 1u : 0u;
  }
  __syncthreads();
  if (threadIdx.x == 0) {
    u32 fw = 0;
    for (int c = 0; c < 32; ++c) fw |= sf[c] << c;
    fwords[b] = fw;
  }
}

// ------------- QKV GEMM: 256x256 tile, BK=64, 8 waves, dbuf LDS + counted vmcnt -------------
// C[m][n] = sum_k A[m][k] * Bt[n][k];  M=8192, N=3072, K=1024. LDS 128 KiB:
// [A|B][dbuf][half(128 rows)][64 k] bf16, XOR-swizzled (slot ^= row&7) via pre-swizzled
// global source (both-sides rule). Schedule per K-tile: vmcnt(8)->barrier->4 quadrant
// phases->barrier->STAGE(t+2): tile t+1's 8 loads stay in flight across barriers (T3/T4).
// Epilogue: Q (pre-scaled 0.125*log2e) / K scatter [B,H,T,D]; V transposed [B,H,D,T].
__global__ __launch_bounds__(512, 2) void qkv_gemm_kernel(
    const u16* __restrict__ A, const u16* __restrict__ Bt,
    const float* __restrict__ bq, const float* __restrict__ bk, const float* __restrict__ bv,
    u16* __restrict__ q_out, u16* __restrict__ k_out, u16* __restrict__ v_out) {
  __shared__ __align__(16) char LDS[131072];
  const int tid = threadIdx.x, lane = tid & 63, w = tid >> 6;
  const int wm = w >> 2, wn = w & 3;
  const int lq = lane & 15, g = lane >> 4;
  const int m0 = blockIdx.x * 256, n0 = blockIdx.y * 256;

  // staging source bases: per-lane, column pre-swizzled (slot ^ row&7)
  const int l3 = lane >> 3;
  const int swb = ((lane & 7) ^ (l3 & 7)) * 16;
  const char* pS[8];
#pragma unroll
  for (int h = 0; h < 2; ++h)
#pragma unroll
    for (int r = 0; r < 2; ++r) {
      int row = h * 128 + r * 64 + w * 8 + l3;
      pS[h * 2 + r]     = (const char*)A  + (size_t)(m0 + row) * 2048 + swb;
      pS[4 + h * 2 + r] = (const char*)Bt + (size_t)(n0 + row) * 2048 + swb;
    }

  auto STAGE = [&](int db, int t) {
    const int off = t * 128;
#pragma unroll
    for (int m = 0; m < 2; ++m)
#pragma unroll
      for (int h = 0; h < 2; ++h)
#pragma unroll
        for (int r = 0; r < 2; ++r)
          __builtin_amdgcn_global_load_lds(
              (const __attribute__((address_space(1))) void*)(pS[m * 4 + h * 2 + r] + off),
              (__attribute__((address_space(3))) void*)(
                  LDS + m * 65536 + db * 32768 + h * 16384 + r * 8192 + w * 1024),
              16, 0, 0);
  };

  // fragment read bases (swizzled read side)
  const int acol0 = (g * 16) ^ ((lq & 7) << 4);
  const int acol1 = (64 + g * 16) ^ ((lq & 7) << 4);
  const int aBase = wm * 16384 + lq * 128;
  const int bBase = 65536 + (wn >> 1) * 16384 + ((wn & 1) * 64 + lq) * 128;

  f32x4 acc[8][4] = {};

  auto TILE = [&](int db, int t) {
    if (t == 15)
      asm volatile("s_waitcnt vmcnt(0)" ::: "memory");
    else
      asm volatile("s_waitcnt vmcnt(8)" ::: "memory");
    asm volatile("s_barrier" ::: "memory");
    const char* la = LDS + db * 32768 + aBase;
    const char* lb = LDS + db * 32768 + bBase;
#pragma unroll
    for (int i4 = 0; i4 < 2; ++i4) {
      bf16x8 af[4][2];
#pragma unroll
      for (int i = 0; i < 4; ++i) {
        af[i][0] = *reinterpret_cast<const bf16x8*>(la + (i4 * 4 + i) * 2048 + acol0);
        af[i][1] = *reinterpret_cast<const bf16x8*>(la + (i4 * 4 + i) * 2048 + acol1);
      }
#pragma unroll
      for (int j2 = 0; j2 < 2; ++j2) {
        bf16x8 bfr[2][2];
#pragma unroll
        for (int j = 0; j < 2; ++j) {
          bfr[j][0] = *reinterpret_cast<const bf16x8*>(lb + (j2 * 2 + j) * 2048 + acol0);
          bfr[j][1] = *reinterpret_cast<const bf16x8*>(lb + (j2 * 2 + j) * 2048 + acol1);
        }
        __builtin_amdgcn_s_setprio(1);
#pragma unroll
        for (int i = 0; i < 4; ++i)
#pragma unroll
          for (int j = 0; j < 2; ++j) {
            f32x4& a = acc[i4 * 4 + i][j2 * 2 + j];
            a = __builtin_amdgcn_mfma_f32_16x16x32_bf16(af[i][0], bfr[j][0], a, 0, 0, 0);
            a = __builtin_amdgcn_mfma_f32_16x16x32_bf16(af[i][1], bfr[j][1], a, 0, 0, 0);
          }
        __builtin_amdgcn_s_setprio(0);
      }
    }
    asm volatile("s_barrier" ::: "memory");
    if (t + 2 < 16) STAGE(db, t + 2);
  };

  STAGE(0, 0);
  STAGE(1, 1);
  for (int t = 0; t < 16; t += 2) {
    TILE(0, t);
    TILE(1, t + 1);
  }

  // epilogue
  const int g3 = n0 >> 10;  // 0:Q 1:K 2:V (uniform per block; 1024 % 256 == 0)
  const int mrow = m0 + wm * 128;
  const int ncol = n0 + wn * 64;
  if (g3 < 2) {
    u16* dst = g3 == 0 ? q_out : k_out;
    const float* bias = g3 == 0 ? bq : bk;
    const float scl = g3 == 0 ? 0.18033688f : 1.0f;  // Q pre-scale: 0.125*log2(e)
#pragma unroll
    for (int i = 0; i < 8; ++i)
#pragma unroll
      for (int j = 0; j < 4; ++j) {
        int n = ncol + j * 16 + lq;
        int h = (n >> 6) & 15, d = n & 63;
        float bb = bias[n & 1023];
#pragma unroll
        for (int r = 0; r < 4; ++r) {
          int m = mrow + i * 16 + g * 4 + r;
          int b = m >> 11, t = m & 2047;
          dst[(((size_t)(b * HH + h)) * TT + t) * DD + d] = f2b((acc[i][j][r] + bb) * scl);
        }
      }
  } else {
    // V transposed [B,H,D,T]: 4 consecutive t per lane -> 8B store
#pragma unroll
    for (int i = 0; i < 8; ++i)
#pragma unroll
      for (int j = 0; j < 4; ++j) {
        int n = ncol + j * 16 + lq;
        int h = (n >> 6) & 15, d = n & 63;
        float bb = bv[n & 1023];
        int mb = mrow + i * 16 + g * 4;
        int b = mb >> 11, t = mb & 2047;
        u16x4 vv;
#pragma unroll
        for (int r = 0; r < 4; ++r) vv[r] = f2b(acc[i][j][r] + bb);
        *reinterpret_cast<u16x4*>(v_out + (((size_t)(b * HH + h)) * DD + d) * TT + t) = vv;
      }
  }
}

// ---------------- proj GEMM: 128x128 tile, BK=32, dbuf LDS + counted vmcnt ----------------
// fp32 out[m*N+n] = acc + bias[n];  M=8192, N=1024, K=1024.
__global__ __launch_bounds__(256) void proj_gemm_kernel(
    const u16* __restrict__ A, const u16* __restrict__ Bt,
    const float* __restrict__ bias, float* __restrict__ f_out) {
  __shared__ u16 As[2][128 * 32];
  __shared__ u16 Bs[2][128 * 32];
  const int tid = threadIdx.x, lane = tid & 63, w = tid >> 6;
  const int wm = w >> 1, wn = w & 1;
  const int m0 = blockIdx.x * 128, n0 = blockIdx.y * 128;
  const int lrow = lane >> 2, lcol = (lane & 3) * 8;
  f32x4 acc[4][4] = {};

  auto STAGE = [&](int db, int kt) {
    const int k0 = kt * 32;
#pragma unroll
    for (int r = 0; r < 2; ++r) {
      int row = r * 64 + w * 16 + lrow;
      __builtin_amdgcn_global_load_lds(
          (const __attribute__((address_space(1))) void*)(A + (size_t)(m0 + row) * CC + k0 + lcol),
          (__attribute__((address_space(3))) void*)(&As[db][(r * 64 + w * 16) * 32]), 16, 0, 0);
      __builtin_amdgcn_global_load_lds(
          (const __attribute__((address_space(1))) void*)(Bt + (size_t)(n0 + row) * CC + k0 + lcol),
          (__attribute__((address_space(3))) void*)(&Bs[db][(r * 64 + w * 16) * 32]), 16, 0, 0);
    }
  };

  STAGE(0, 0);
  STAGE(1, 1);
  for (int kt = 0; kt < 32; ++kt) {
    if (kt == 31)
      asm volatile("s_waitcnt vmcnt(0)" ::: "memory");
    else
      asm volatile("s_waitcnt vmcnt(4)" ::: "memory");
    asm volatile("s_barrier" ::: "memory");
    const int db = kt & 1;
    bf16x8 af[4], bfr[4];
#pragma unroll
    for (int i = 0; i < 4; ++i) {
      af[i] = *reinterpret_cast<const bf16x8*>(&As[db][(wm * 64 + i * 16 + (lane & 15)) * 32 + (lane >> 4) * 8]);
      bfr[i] = *reinterpret_cast<const bf16x8*>(&Bs[db][(wn * 64 + i * 16 + (lane & 15)) * 32 + (lane >> 4) * 8]);
    }
    __builtin_amdgcn_s_setprio(1);
#pragma unroll
    for (int i = 0; i < 4; ++i)
#pragma unroll
      for (int j = 0; j < 4; ++j)
        acc[i][j] = __builtin_amdgcn_mfma_f32_16x16x32_bf16(af[i], bfr[j], acc[i][j], 0, 0, 0);
    __builtin_amdgcn_s_setprio(0);
    asm volatile("s_barrier" ::: "memory");
    if (kt + 2 < 32) STAGE(db, kt + 2);
  }

  const int mrow = m0 + wm * 64;
  const int ncol = n0 + wn * 64;
#pragma unroll
  for (int i = 0; i < 4; ++i)
#pragma unroll
    for (int j = 0; j < 4; ++j)
#pragma unroll
      for (int r = 0; r < 4; ++r) {
        int m = mrow + i * 16 + (lane >> 4) * 4 + r;
        int n = ncol + j * 16 + (lane & 15);
        f_out[(size_t)m * CC + n] = acc[i][j][r] + bias[n];
      }
}

// ------- causal flash attention: LDS-staged K/V double-buffer + counted vmcnt -------
// (unchanged from r8 — validated)
__global__ __launch_bounds__(256, 2) void attn_kernel(
    const u16* __restrict__ Q, const u16* __restrict__ K, const u16* __restrict__ Vt,
    const float* __restrict__ gm, const u32* __restrict__ fwords, u16* __restrict__ Y) {
  __shared__ __align__(16) char LDS[51200];
  const int flat = blockIdx.x;
  const int xcd = flat & 7, idx = flat >> 3;
  const int bh = xcd * 8 + (idx & 7);
  const int jb = 15 - (idx >> 3);
  const int b = bh >> 4, h = bh & 15;
  const int tid = threadIdx.x, lane = tid & 63, w = tid >> 6;
  const int lq = lane & 15, g = lane >> 4;
  const int qt = 4 * jb + w;
  const int q0 = qt * 32;
  const int nkt = (qt >> 1) + 1;
  const int nktm = 2 * jb + 2;
  const u32 fw = fwords[b];

  const u16* Qb = Q + (size_t)bh * TT * DD;
  const char* Kb = (const char*)(K + (size_t)bh * TT * DD);
  const char* Vb = (const char*)(Vt + (size_t)bh * DD * TT);

  const int l3 = lane >> 3, l7 = lane & 7;
  const int swb = (l7 * 16) ^ (l3 << 4);
  const char* kp0 = Kb + (2 * w + 0) * 1024 + l3 * 128 + swb;
  const char* kp1 = Kb + (2 * w + 1) * 1024 + l3 * 128 + swb;
  const char* vp0 = Vb + (size_t)((2 * w + 0) * 8 + l3) * 4096 + swb;
  const char* vp1 = Vb + (size_t)((2 * w + 1) * 8 + l3) * 4096 + swb;

  const int sw2 = (lq & 7) << 4;
  const int fb0 = lq * 128 + ((g * 16) ^ sw2);
  const int fb1 = lq * 128 + (((64) + g * 16) ^ sw2);
  const int pwb = 32768 + w * 4608 + lq * 144 + g * 8;
  const int prb = 32768 + w * 4608 + lq * 144 + g * 16;

  auto STAGE = [&](int buf, int kt2) {
    const int ko = kt2 * 8192, vo = kt2 * 128, lb = buf * 8192;
    __builtin_amdgcn_global_load_lds(
        (const __attribute__((address_space(1))) void*)(kp0 + ko),
        (__attribute__((address_space(3))) void*)(LDS + lb + (2 * w + 0) * 1024), 16, 0, 0);
    __builtin_amdgcn_global_load_lds(
        (const __attribute__((address_space(1))) void*)(kp1 + ko),
        (__attribute__((address_space(3))) void*)(LDS + lb + (2 * w + 1) * 1024), 16, 0, 0);
    __builtin_amdgcn_global_load_lds(
        (const __attribute__((address_space(1))) void*)(vp0 + vo),
        (__attribute__((address_space(3))) void*)(LDS + 16384 + lb + (2 * w + 0) * 1024), 16, 0, 0);
    __builtin_amdgcn_global_load_lds(
        (const __attribute__((address_space(1))) void*)(vp1 + vo),
        (__attribute__((address_space(3))) void*)(LDS + 16384 + lb + (2 * w + 1) * 1024), 16, 0, 0);
  };

  bf16x8 qf[2][2];
#pragma unroll
  for (int n = 0; n < 2; ++n)
#pragma unroll
    for (int ks = 0; ks < 2; ++ks)
      qf[n][ks] = *reinterpret_cast<const bf16x8*>(
          Qb + (size_t)(q0 + n * 16 + lq) * DD + ks * 32 + g * 8);

  f32x4 o[4][2] = {};
  float mrun[2] = {-1e30f, -1e30f};
  float lrun[2] = {0.f, 0.f};
  const f32x4 z4 = {0.f, 0.f, 0.f, 0.f};

  STAGE(0, 0);
  STAGE(1, 1);

  auto TILE = [&](int BUF, int kt) {
    if (kt < nktm - 1)
      asm volatile("s_waitcnt vmcnt(4)" ::: "memory");
    else
      asm volatile("s_waitcnt vmcnt(0)" ::: "memory");
    asm volatile("s_barrier" ::: "memory");

    if (kt < nkt) {
      const int kv0 = kt * 64;
      bf16x8 kf0[4], kf1[4];
#pragma unroll
      for (int m = 0; m < 4; ++m) {
        kf0[m] = *reinterpret_cast<const bf16x8*>(LDS + BUF * 8192 + m * 2048 + fb0);
        kf1[m] = *reinterpret_cast<const bf16x8*>(LDS + BUF * 8192 + m * 2048 + fb1);
      }
      f32x4 s[4][2];
      __builtin_amdgcn_s_setprio(1);
#pragma unroll
      for (int m = 0; m < 4; ++m)
#pragma unroll
        for (int n = 0; n < 2; ++n) {
          s[m][n] = __builtin_amdgcn_mfma_f32_16x16x32_bf16(kf0[m], qf[n][0], z4, 0, 0, 0);
          s[m][n] = __builtin_amdgcn_mfma_f32_16x16x32_bf16(kf1[m], qf[n][1], s[m][n], 0, 0, 0);
        }
      __builtin_amdgcn_s_setprio(0);

      if (!((fw >> kt) & 1u)) {
#pragma unroll
        for (int m = 0; m < 4; ++m) {
          float4 mv = *reinterpret_cast<const float4*>(gm + b * TT + kv0 + m * 16 + g * 4);
#pragma unroll
          for (int n = 0; n < 2; ++n) {
            s[m][n][0] += mv.x; s[m][n][1] += mv.y;
            s[m][n][2] += mv.z; s[m][n][3] += mv.w;
          }
        }
      }
      if (kt == nkt - 1) {
#pragma unroll
        for (int n = 0; n < 2; ++n) {
          const int q = q0 + n * 16 + lq;
#pragma unroll
          for (int m = 0; m < 4; ++m)
#pragma unroll
            for (int r = 0; r < 4; ++r) {
              int kv = kv0 + m * 16 + g * 4 + r;
              s[m][n][r] = (kv <= q) ? s[m][n][r] : -1e30f;
            }
        }
      }

#pragma unroll
      for (int n = 0; n < 2; ++n) {
        float rm = fmaxf(fmaxf(fmaxf(s[0][n][0], s[0][n][1]), fmaxf(s[0][n][2], s[0][n][3])),
                         fmaxf(fmaxf(s[1][n][0], s[1][n][1]), fmaxf(s[1][n][2], s[1][n][3])));
        float rm2 = fmaxf(fmaxf(fmaxf(s[2][n][0], s[2][n][1]), fmaxf(s[2][n][2], s[2][n][3])),
                          fmaxf(fmaxf(s[3][n][0], s[3][n][1]), fmaxf(s[3][n][2], s[3][n][3])));
        rm = fmaxf(rm, rm2);
        if (!__all(rm <= mrun[n] + 8.f)) {
          float rg = fmaxf(rm, __shfl_xor(rm, 16));
          rg = fmaxf(rg, __shfl_xor(rg, 32));
          float mnew = fmaxf(mrun[n], rg);
          float corr = __builtin_exp2f(mrun[n] - mnew);
          mrun[n] = mnew;
          lrun[n] *= corr;
#pragma unroll
          for (int nd = 0; nd < 4; ++nd)
#pragma unroll
            for (int r = 0; r < 4; ++r) o[nd][n][r] *= corr;
        }
        const float mn = mrun[n];
        float rs = 0.f;
#pragma unroll
        for (int m = 0; m < 4; ++m) {
          float p0 = __builtin_exp2f(s[m][n][0] - mn);
          float p1 = __builtin_exp2f(s[m][n][1] - mn);
          float p2 = __builtin_exp2f(s[m][n][2] - mn);
          float p3 = __builtin_exp2f(s[m][n][3] - mn);
          rs += (p0 + p1) + (p2 + p3);
          u32 wa, wb;
          asm("v_cvt_pk_bf16_f32 %0, %1, %2" : "=v"(wa) : "v"(p0), "v"(p1));
          asm("v_cvt_pk_bf16_f32 %0, %1, %2" : "=v"(wb) : "v"(p2), "v"(p3));
          uint2 pw; pw.x = wa; pw.y = wb;
          *reinterpret_cast<uint2*>(LDS + pwb + n * 2304 + m * 32) = pw;
        }
        lrun[n] += rs;
      }

      asm volatile("s_waitcnt lgkmcnt(0)" ::: "memory");
      __builtin_amdgcn_sched_barrier(0);

      __builtin_amdgcn_s_setprio(1);
#pragma unroll
      for (int ks = 0; ks < 2; ++ks) {
        const int fb = ks ? fb1 : fb0;
        bf16x8 pf0 = *reinterpret_cast<const bf16x8*>(LDS + prb + 0 * 2304 + ks * 64);
        bf16x8 pf1 = *reinterpret_cast<const bf16x8*>(LDS + prb + 1 * 2304 + ks * 64);
#pragma unroll
        for (int nd = 0; nd < 4; ++nd) {
          bf16x8 vf = *reinterpret_cast<const bf16x8*>(LDS + 16384 + BUF * 8192 + nd * 2048 + fb);
          o[nd][0] = __builtin_amdgcn_mfma_f32_16x16x32_bf16(vf, pf0, o[nd][0], 0, 0, 0);
          o[nd][1] = __builtin_amdgcn_mfma_f32_16x16x32_bf16(vf, pf1, o[nd][1], 0, 0, 0);
        }
      }
      __builtin_amdgcn_s_setprio(0);
    }

    asm volatile("s_barrier" ::: "memory");
    if (kt + 2 < nktm) STAGE(BUF, kt + 2);
  };

  for (int kt = 0; kt < nktm; kt += 2) {
    TILE(0, kt);
    TILE(1, kt + 1);
  }

#pragma unroll
  for (int n = 0; n < 2; ++n) {
    float l = lrun[n];
    l += __shfl_xor(l, 16);
    l += __shfl_xor(l, 32);
    float inv = 1.0f / l;
    const int q = q0 + n * 16 + lq;
#pragma unroll
    for (int nd = 0; nd < 4; ++nd) {
      u16x4 yv;
#pragma unroll
      for (int r = 0; r < 4; ++r) yv[r] = bfc(o[nd][n][r] * inv);
      *reinterpret_cast<u16x4*>(
          Y + ((size_t)(b * TT + q)) * CC + h * DD + nd * 16 + g * 4) = yv;
    }
  }
}

extern "C" void kernel_launch(void* const* d_in, const int* in_sizes, int n_in,
                              void* d_out, int out_size, void* d_ws, size_t ws_size,
                              hipStream_t stream) {
  const float* x  = (const float*)d_in[0];
  const int*   am = (const int*)d_in[1];
  const float* Wq = (const float*)d_in[2];
  const float* bq = (const float*)d_in[3];
  const float* Wk = (const float*)d_in[4];
  const float* bk = (const float*)d_in[5];
  const float* Wv = (const float*)d_in[6];
  const float* bv = (const float*)d_in[7];
  const float* Wp = (const float*)d_in[8];
  const float* bp = (const float*)d_in[9];
  float* out = (float*)d_out;

  char* ws = (char*)d_ws;
  u16* xb    = (u16*)(ws);                        // 16 MB  [8192][1024] bf16
  u16* wqkvT = (u16*)(ws + (16ull << 20));        //  6 MB  [3072][1024] bf16 (W^T)
  u16* wpT   = (u16*)(ws + (22ull << 20));        //  2 MB  [1024][1024] bf16 (Wp^T)
  u16* qw    = (u16*)(ws + (24ull << 20));        // 16 MB  [B,H,T,D] bf16 (pre-scaled)
  u16* kw    = (u16*)(ws + (40ull << 20));        // 16 MB  [B,H,T,D] bf16
  u16* vw    = (u16*)(ws + (56ull << 20));        // 16 MB  [B,H,D,T] bf16 (transposed!)
  u16* yb    = (u16*)(ws + (72ull << 20));        // 16 MB  [B,T,C] bf16
  float* gm  = (float*)d_out;                     // 32 KB [B][T] additive mask (dead until proj)
  u32* fwords = (u32*)((char*)d_out + (64ull << 10));  // [B] chunk-valid bitmask

  mask_prep_kernel<<<dim3(BB), 256, 0, stream>>>(am, gm, fwords);
  {
    int n8 = BB * TT * CC / 8;
    cvt_bf16_kernel<<<n8 / 256, 256, 0, stream>>>(x, xb, n8);
  }
  transp_w_kernel<<<dim3(32, 32, 4), 256, 0, stream>>>(Wq, Wk, Wv, Wp, wqkvT, wpT);
  qkv_gemm_kernel<<<dim3(32, 12), 512, 0, stream>>>(
      xb, wqkvT, bq, bk, bv, qw, kw, vw);
  attn_kernel<<<dim3(1024), 256, 0, stream>>>(qw, kw, vw, gm, fwords, yb);
  proj_gemm_kernel<<<dim3(64, 8), 256, 0, stream>>>(yb, wpT, bp, out);
}

// Round 10
// 173.968 us; speedup vs baseline: 1.8208x; 1.0704x over previous
//
#include <hip/hip_runtime.h>

#define BB 4
#define TT 2048
#define CC 1024
#define HH 16
#define DD 64

typedef unsigned short u16;
typedef unsigned int u32;
typedef __bf16 bf16;
typedef __attribute__((ext_vector_type(8))) bf16 bf16x8;
typedef __attribute__((ext_vector_type(8))) u16 u16x8;
typedef __attribute__((ext_vector_type(4))) u16 u16x4;
typedef __attribute__((ext_vector_type(4))) float f32x4;

static __device__ __forceinline__ u16 f2b(float f) {
  unsigned u = __builtin_bit_cast(unsigned, f);
  u += 0x7fffu + ((u >> 16) & 1u);
  return (u16)(u >> 16);
}
static __device__ __forceinline__ u16 bfc(float f) {
  return __builtin_bit_cast(u16, (__bf16)f);
}
static __device__ __forceinline__ float max3f(float a, float b, float c) {
  float d;
  asm("v_max3_f32 %0, %1, %2, %3" : "=v"(d) : "v"(a), "v"(b), "v"(c));
  return d;
}

// ---- fused prep: [0,4096) cvt x->bf16 | [4096,8192) transpose W | [8192,8196) mask ----
__global__ __launch_bounds__(256) void prep_kernel(
    const float* __restrict__ x, const int* __restrict__ am,
    const float* __restrict__ w0, const float* __restrict__ w1,
    const float* __restrict__ w2, const float* __restrict__ w3,
    u16* __restrict__ xb, u16* __restrict__ wqkvT, u16* __restrict__ wpT,
    float* __restrict__ gm, u32* __restrict__ fwords) {
  __shared__ float t[32][33];
  const int bid = blockIdx.x, tid = threadIdx.x;
  if (bid < 4096) {
    // cvt: 8 f32 -> 8 bf16 per thread
    int i = bid * 256 + tid;
    const float4* p4 = reinterpret_cast<const float4*>(x) + (size_t)i * 2;
    float4 a = p4[0], b = p4[1];
    u16x8 o;
    o[0] = f2b(a.x); o[1] = f2b(a.y); o[2] = f2b(a.z); o[3] = f2b(a.w);
    o[4] = f2b(b.x); o[5] = f2b(b.y); o[6] = f2b(b.z); o[7] = f2b(b.w);
    *reinterpret_cast<u16x8*>(xb + (size_t)i * 8) = o;
  } else if (bid < 8192) {
    int r2 = bid - 4096;
    int z = r2 >> 10, rem = r2 & 1023;
    int k0 = (rem & 31) * 32, n0 = (rem >> 5) * 32;
    const float* src = z == 0 ? w0 : z == 1 ? w1 : z == 2 ? w2 : w3;
    u16* dst = z < 3 ? wqkvT + (size_t)z * CC * CC : wpT;
    int tx = tid & 31, ty = tid >> 5;
#pragma unroll
    for (int i = 0; i < 4; ++i)
      t[ty + i * 8][tx] = src[(size_t)(k0 + ty + i * 8) * CC + n0 + tx];
    __syncthreads();
#pragma unroll
    for (int i = 0; i < 4; ++i)
      dst[(size_t)(n0 + ty + i * 8) * CC + k0 + tx] = f2b(t[tx][ty + i * 8]);
  } else {
    __shared__ u32 sf[32];
    int b = bid - 8192;
    int lane = tid & 63, w = tid >> 6;
#pragma unroll
    for (int j = 0; j < 8; ++j) {
      int c = w * 8 + j;
      int i = c * 64 + lane;
      int v = am[b * TT + i];
      gm[b * TT + i] = v ? 0.f : -1e30f;
      unsigned long long bal = __ballot(v != 0);
      if (lane == 0) sf[c] = (bal == ~0ull) ? 1u : 0u;
    }
    __syncthreads();
    if (tid == 0) {
      u32 fw = 0;
      for (int c = 0; c < 32; ++c) fw |= sf[c] << c;
      fwords[b] = fw;
    }
  }
}

// ------------- QKV GEMM: 256x256 tile, BK=64, 8 waves, dbuf LDS + counted vmcnt -------------
__global__ __launch_bounds__(512, 2) void qkv_gemm_kernel(
    const u16* __restrict__ A, const u16* __restrict__ Bt,
    const float* __restrict__ bq, const float* __restrict__ bk, const float* __restrict__ bv,
    u16* __restrict__ q_out, u16* __restrict__ k_out, u16* __restrict__ v_out) {
  __shared__ __align__(16) char LDS[131072];
  const int tid = threadIdx.x, lane = tid & 63, w = tid >> 6;
  const int wm = w >> 2, wn = w & 3;
  const int lq = lane & 15, g = lane >> 4;
  const int m0 = blockIdx.x * 256, n0 = blockIdx.y * 256;

  const int l3 = lane >> 3;
  const int swb = ((lane & 7) ^ (l3 & 7)) * 16;
  const char* pS[8];
#pragma unroll
  for (int h = 0; h < 2; ++h)
#pragma unroll
    for (int r = 0; r < 2; ++r) {
      int row = h * 128 + r * 64 + w * 8 + l3;
      pS[h * 2 + r]     = (const char*)A  + (size_t)(m0 + row) * 2048 + swb;
      pS[4 + h * 2 + r] = (const char*)Bt + (size_t)(n0 + row) * 2048 + swb;
    }

  auto STAGE = [&](int db, int t) {
    const int off = t * 128;
#pragma unroll
    for (int m = 0; m < 2; ++m)
#pragma unroll
      for (int h = 0; h < 2; ++h)
#pragma unroll
        for (int r = 0; r < 2; ++r)
          __builtin_amdgcn_global_load_lds(
              (const __attribute__((address_space(1))) void*)(pS[m * 4 + h * 2 + r] + off),
              (__attribute__((address_space(3))) void*)(
                  LDS + m * 65536 + db * 32768 + h * 16384 + r * 8192 + w * 1024),
              16, 0, 0);
  };

  const int acol0 = (g * 16) ^ ((lq & 7) << 4);
  const int acol1 = (64 + g * 16) ^ ((lq & 7) << 4);
  const int aBase = wm * 16384 + lq * 128;
  const int bBase = 65536 + (wn >> 1) * 16384 + ((wn & 1) * 64 + lq) * 128;

  f32x4 acc[8][4] = {};

  auto TILE = [&](int db, int t) {
    if (t == 15)
      asm volatile("s_waitcnt vmcnt(0)" ::: "memory");
    else
      asm volatile("s_waitcnt vmcnt(8)" ::: "memory");
    asm volatile("s_barrier" ::: "memory");
    const char* la = LDS + db * 32768 + aBase;
    const char* lb = LDS + db * 32768 + bBase;
#pragma unroll
    for (int i4 = 0; i4 < 2; ++i4) {
      bf16x8 af[4][2];
#pragma unroll
      for (int i = 0; i < 4; ++i) {
        af[i][0] = *reinterpret_cast<const bf16x8*>(la + (i4 * 4 + i) * 2048 + acol0);
        af[i][1] = *reinterpret_cast<const bf16x8*>(la + (i4 * 4 + i) * 2048 + acol1);
      }
#pragma unroll
      for (int j2 = 0; j2 < 2; ++j2) {
        bf16x8 bfr[2][2];
#pragma unroll
        for (int j = 0; j < 2; ++j) {
          bfr[j][0] = *reinterpret_cast<const bf16x8*>(lb + (j2 * 2 + j) * 2048 + acol0);
          bfr[j][1] = *reinterpret_cast<const bf16x8*>(lb + (j2 * 2 + j) * 2048 + acol1);
        }
        __builtin_amdgcn_s_setprio(1);
#pragma unroll
        for (int i = 0; i < 4; ++i)
#pragma unroll
          for (int j = 0; j < 2; ++j) {
            f32x4& a = acc[i4 * 4 + i][j2 * 2 + j];
            a = __builtin_amdgcn_mfma_f32_16x16x32_bf16(af[i][0], bfr[j][0], a, 0, 0, 0);
            a = __builtin_amdgcn_mfma_f32_16x16x32_bf16(af[i][1], bfr[j][1], a, 0, 0, 0);
          }
        __builtin_amdgcn_s_setprio(0);
      }
    }
    asm volatile("s_barrier" ::: "memory");
    if (t + 2 < 16) STAGE(db, t + 2);
  };

  STAGE(0, 0);
  STAGE(1, 1);
  for (int t = 0; t < 16; t += 2) {
    TILE(0, t);
    TILE(1, t + 1);
  }

  const int g3 = n0 >> 10;  // 0:Q 1:K 2:V (uniform per block)
  const int mrow = m0 + wm * 128;
  const int ncol = n0 + wn * 64;
  if (g3 < 2) {
    u16* dst = g3 == 0 ? q_out : k_out;
    const float* bias = g3 == 0 ? bq : bk;
    const float scl = g3 == 0 ? 0.18033688f : 1.0f;  // Q pre-scale: 0.125*log2(e)
#pragma unroll
    for (int i = 0; i < 8; ++i)
#pragma unroll
      for (int j = 0; j < 4; ++j) {
        int n = ncol + j * 16 + lq;
        int h = (n >> 6) & 15, d = n & 63;
        float bb = bias[n & 1023];
#pragma unroll
        for (int r = 0; r < 4; ++r) {
          int m = mrow + i * 16 + g * 4 + r;
          int b = m >> 11, t = m & 2047;
          dst[(((size_t)(b * HH + h)) * TT + t) * DD + d] = f2b((acc[i][j][r] + bb) * scl);
        }
      }
  } else {
#pragma unroll
    for (int i = 0; i < 8; ++i)
#pragma unroll
      for (int j = 0; j < 4; ++j) {
        int n = ncol + j * 16 + lq;
        int h = (n >> 6) & 15, d = n & 63;
        float bb = bv[n & 1023];
        int mb = mrow + i * 16 + g * 4;
        int b = mb >> 11, t = mb & 2047;
        u16x4 vv;
#pragma unroll
        for (int r = 0; r < 4; ++r) vv[r] = f2b(acc[i][j][r] + bb);
        *reinterpret_cast<u16x4*>(v_out + (((size_t)(b * HH + h)) * DD + d) * TT + t) = vv;
      }
  }
}

// ---------------- proj GEMM: 128x128 tile, BK=32, dbuf LDS + counted vmcnt ----------------
__global__ __launch_bounds__(256) void proj_gemm_kernel(
    const u16* __restrict__ A, const u16* __restrict__ Bt,
    const float* __restrict__ bias, float* __restrict__ f_out) {
  __shared__ u16 As[2][128 * 32];
  __shared__ u16 Bs[2][128 * 32];
  const int tid = threadIdx.x, lane = tid & 63, w = tid >> 6;
  const int wm = w >> 1, wn = w & 1;
  const int m0 = blockIdx.x * 128, n0 = blockIdx.y * 128;
  const int lrow = lane >> 2, lcol = (lane & 3) * 8;
  f32x4 acc[4][4] = {};

  auto STAGE = [&](int db, int kt) {
    const int k0 = kt * 32;
#pragma unroll
    for (int r = 0; r < 2; ++r) {
      int row = r * 64 + w * 16 + lrow;
      __builtin_amdgcn_global_load_lds(
          (const __attribute__((address_space(1))) void*)(A + (size_t)(m0 + row) * CC + k0 + lcol),
          (__attribute__((address_space(3))) void*)(&As[db][(r * 64 + w * 16) * 32]), 16, 0, 0);
      __builtin_amdgcn_global_load_lds(
          (const __attribute__((address_space(1))) void*)(Bt + (size_t)(n0 + row) * CC + k0 + lcol),
          (__attribute__((address_space(3))) void*)(&Bs[db][(r * 64 + w * 16) * 32]), 16, 0, 0);
    }
  };

  STAGE(0, 0);
  STAGE(1, 1);
  for (int kt = 0; kt < 32; ++kt) {
    if (kt == 31)
      asm volatile("s_waitcnt vmcnt(0)" ::: "memory");
    else
      asm volatile("s_waitcnt vmcnt(4)" ::: "memory");
    asm volatile("s_barrier" ::: "memory");
    const int db = kt & 1;
    bf16x8 af[4], bfr[4];
#pragma unroll
    for (int i = 0; i < 4; ++i) {
      af[i] = *reinterpret_cast<const bf16x8*>(&As[db][(wm * 64 + i * 16 + (lane & 15)) * 32 + (lane >> 4) * 8]);
      bfr[i] = *reinterpret_cast<const bf16x8*>(&Bs[db][(wn * 64 + i * 16 + (lane & 15)) * 32 + (lane >> 4) * 8]);
    }
    __builtin_amdgcn_s_setprio(1);
#pragma unroll
    for (int i = 0; i < 4; ++i)
#pragma unroll
      for (int j = 0; j < 4; ++j)
        acc[i][j] = __builtin_amdgcn_mfma_f32_16x16x32_bf16(af[i], bfr[j], acc[i][j], 0, 0, 0);
    __builtin_amdgcn_s_setprio(0);
    asm volatile("s_barrier" ::: "memory");
    if (kt + 2 < 32) STAGE(db, kt + 2);
  }

  const int mrow = m0 + wm * 64;
  const int ncol = n0 + wn * 64;
#pragma unroll
  for (int i = 0; i < 4; ++i)
#pragma unroll
    for (int j = 0; j < 4; ++j)
#pragma unroll
      for (int r = 0; r < 4; ++r) {
        int m = mrow + i * 16 + (lane >> 4) * 4 + r;
        int n = ncol + j * 16 + (lane & 15);
        f_out[(size_t)m * CC + n] = acc[i][j][r] + bias[n];
      }
}

// ------- causal flash attention: LDS-staged K/V dbuf + counted vmcnt -------
// r10: row-sum l via ones-MFMA (no VALU adds, no epilogue reduce), v_max3 max tree.
__global__ __launch_bounds__(256, 2) void attn_kernel(
    const u16* __restrict__ Q, const u16* __restrict__ K, const u16* __restrict__ Vt,
    const float* __restrict__ gm, const u32* __restrict__ fwords, u16* __restrict__ Y) {
  __shared__ __align__(16) char LDS[51200];
  const int flat = blockIdx.x;
  const int xcd = flat & 7, idx = flat >> 3;
  const int bh = xcd * 8 + (idx & 7);
  const int jb = 15 - (idx >> 3);
  const int b = bh >> 4, h = bh & 15;
  const int tid = threadIdx.x, lane = tid & 63, w = tid >> 6;
  const int lq = lane & 15, g = lane >> 4;
  const int qt = 4 * jb + w;
  const int q0 = qt * 32;
  const int nkt = (qt >> 1) + 1;
  const int nktm = 2 * jb + 2;
  const u32 fw = fwords[b];

  const u16* Qb = Q + (size_t)bh * TT * DD;
  const char* Kb = (const char*)(K + (size_t)bh * TT * DD);
  const char* Vb = (const char*)(Vt + (size_t)bh * DD * TT);

  const int l3 = lane >> 3, l7 = lane & 7;
  const int swb = (l7 * 16) ^ (l3 << 4);
  const char* kp0 = Kb + (2 * w + 0) * 1024 + l3 * 128 + swb;
  const char* kp1 = Kb + (2 * w + 1) * 1024 + l3 * 128 + swb;
  const char* vp0 = Vb + (size_t)((2 * w + 0) * 8 + l3) * 4096 + swb;
  const char* vp1 = Vb + (size_t)((2 * w + 1) * 8 + l3) * 4096 + swb;

  const int sw2 = (lq & 7) << 4;
  const int fb0 = lq * 128 + ((g * 16) ^ sw2);
  const int fb1 = lq * 128 + (((64) + g * 16) ^ sw2);
  const int pwb = 32768 + w * 4608 + lq * 144 + g * 8;
  const int prb = 32768 + w * 4608 + lq * 144 + g * 16;

  auto STAGE = [&](int buf, int kt2) {
    const int ko = kt2 * 8192, vo = kt2 * 128, lb = buf * 8192;
    __builtin_amdgcn_global_load_lds(
        (const __attribute__((address_space(1))) void*)(kp0 + ko),
        (__attribute__((address_space(3))) void*)(LDS + lb + (2 * w + 0) * 1024), 16, 0, 0);
    __builtin_amdgcn_global_load_lds(
        (const __attribute__((address_space(1))) void*)(kp1 + ko),
        (__attribute__((address_space(3))) void*)(LDS + lb + (2 * w + 1) * 1024), 16, 0, 0);
    __builtin_amdgcn_global_load_lds(
        (const __attribute__((address_space(1))) void*)(vp0 + vo),
        (__attribute__((address_space(3))) void*)(LDS + 16384 + lb + (2 * w + 0) * 1024), 16, 0, 0);
    __builtin_amdgcn_global_load_lds(
        (const __attribute__((address_space(1))) void*)(vp1 + vo),
        (__attribute__((address_space(3))) void*)(LDS + 16384 + lb + (2 * w + 1) * 1024), 16, 0, 0);
  };

  bf16x8 qf[2][2];
#pragma unroll
  for (int n = 0; n < 2; ++n)
#pragma unroll
    for (int ks = 0; ks < 2; ++ks)
      qf[n][ks] = *reinterpret_cast<const bf16x8*>(
          Qb + (size_t)(q0 + n * 16 + lq) * DD + ks * 32 + g * 8);

  // all-ones A-operand fragment for the l row-sum MFMA
  const u16x8 onesu = {0x3F80, 0x3F80, 0x3F80, 0x3F80, 0x3F80, 0x3F80, 0x3F80, 0x3F80};
  const bf16x8 ones = __builtin_bit_cast(bf16x8, onesu);

  f32x4 o[4][2] = {};
  f32x4 l_acc[2] = {};  // row-sum accumulator (all 4 regs identical)
  float mrun[2] = {-1e30f, -1e30f};
  const f32x4 z4 = {0.f, 0.f, 0.f, 0.f};

  STAGE(0, 0);
  STAGE(1, 1);

  auto TILE = [&](int BUF, int kt) {
    if (kt < nktm - 1)
      asm volatile("s_waitcnt vmcnt(4)" ::: "memory");
    else
      asm volatile("s_waitcnt vmcnt(0)" ::: "memory");
    asm volatile("s_barrier" ::: "memory");

    if (kt < nkt) {
      const int kv0 = kt * 64;
      bf16x8 kf0[4], kf1[4];
#pragma unroll
      for (int m = 0; m < 4; ++m) {
        kf0[m] = *reinterpret_cast<const bf16x8*>(LDS + BUF * 8192 + m * 2048 + fb0);
        kf1[m] = *reinterpret_cast<const bf16x8*>(LDS + BUF * 8192 + m * 2048 + fb1);
      }
      f32x4 s[4][2];
      __builtin_amdgcn_s_setprio(1);
#pragma unroll
      for (int m = 0; m < 4; ++m)
#pragma unroll
        for (int n = 0; n < 2; ++n) {
          s[m][n] = __builtin_amdgcn_mfma_f32_16x16x32_bf16(kf0[m], qf[n][0], z4, 0, 0, 0);
          s[m][n] = __builtin_amdgcn_mfma_f32_16x16x32_bf16(kf1[m], qf[n][1], s[m][n], 0, 0, 0);
        }
      __builtin_amdgcn_s_setprio(0);

      if (!((fw >> kt) & 1u)) {
#pragma unroll
        for (int m = 0; m < 4; ++m) {
          float4 mv = *reinterpret_cast<const float4*>(gm + b * TT + kv0 + m * 16 + g * 4);
#pragma unroll
          for (int n = 0; n < 2; ++n) {
            s[m][n][0] += mv.x; s[m][n][1] += mv.y;
            s[m][n][2] += mv.z; s[m][n][3] += mv.w;
          }
        }
      }
      if (kt == nkt - 1) {
#pragma unroll
        for (int n = 0; n < 2; ++n) {
          const int q = q0 + n * 16 + lq;
#pragma unroll
          for (int m = 0; m < 4; ++m)
#pragma unroll
            for (int r = 0; r < 4; ++r) {
              int kv = kv0 + m * 16 + g * 4 + r;
              s[m][n][r] = (kv <= q) ? s[m][n][r] : -1e30f;
            }
        }
      }

      // online softmax (log2 domain via pre-scaled Q), max3 tree + gated defer-rescale
#pragma unroll
      for (int n = 0; n < 2; ++n) {
        float m1 = max3f(s[0][n][0], s[0][n][1], s[0][n][2]);
        float m2 = max3f(s[0][n][3], s[1][n][0], s[1][n][1]);
        float m3 = max3f(s[1][n][2], s[1][n][3], s[2][n][0]);
        float m4 = max3f(s[2][n][1], s[2][n][2], s[2][n][3]);
        float m5 = max3f(s[3][n][0], s[3][n][1], s[3][n][2]);
        float rm = fmaxf(max3f(m1, m2, m3), max3f(m4, m5, s[3][n][3]));
        if (!__all(rm <= mrun[n] + 8.f)) {
          float rg = fmaxf(rm, __shfl_xor(rm, 16));
          rg = fmaxf(rg, __shfl_xor(rg, 32));
          float mnew = fmaxf(mrun[n], rg);
          float corr = __builtin_exp2f(mrun[n] - mnew);
          mrun[n] = mnew;
          l_acc[n] *= corr;
#pragma unroll
          for (int nd = 0; nd < 4; ++nd)
#pragma unroll
            for (int r = 0; r < 4; ++r) o[nd][n][r] *= corr;
        }
        const float mn = mrun[n];
#pragma unroll
        for (int m = 0; m < 4; ++m) {
          float p0 = __builtin_exp2f(s[m][n][0] - mn);
          float p1 = __builtin_exp2f(s[m][n][1] - mn);
          float p2 = __builtin_exp2f(s[m][n][2] - mn);
          float p3 = __builtin_exp2f(s[m][n][3] - mn);
          u32 wa, wb;
          asm("v_cvt_pk_bf16_f32 %0, %1, %2" : "=v"(wa) : "v"(p0), "v"(p1));
          asm("v_cvt_pk_bf16_f32 %0, %1, %2" : "=v"(wb) : "v"(p2), "v"(p3));
          uint2 pw; pw.x = wa; pw.y = wb;
          *reinterpret_cast<uint2*>(LDS + pwb + n * 2304 + m * 32) = pw;
        }
      }

      asm volatile("s_waitcnt lgkmcnt(0)" ::: "memory");
      __builtin_amdgcn_sched_barrier(0);

      // O^T += V^T * P^T ;  l_acc += ones * P^T  (row-sum via matrix pipe)
      __builtin_amdgcn_s_setprio(1);
#pragma unroll
      for (int ks = 0; ks < 2; ++ks) {
        const int fb = ks ? fb1 : fb0;
        bf16x8 pf0 = *reinterpret_cast<const bf16x8*>(LDS + prb + 0 * 2304 + ks * 64);
        bf16x8 pf1 = *reinterpret_cast<const bf16x8*>(LDS + prb + 1 * 2304 + ks * 64);
#pragma unroll
        for (int nd = 0; nd < 4; ++nd) {
          bf16x8 vf = *reinterpret_cast<const bf16x8*>(LDS + 16384 + BUF * 8192 + nd * 2048 + fb);
          o[nd][0] = __builtin_amdgcn_mfma_f32_16x16x32_bf16(vf, pf0, o[nd][0], 0, 0, 0);
          o[nd][1] = __builtin_amdgcn_mfma_f32_16x16x32_bf16(vf, pf1, o[nd][1], 0, 0, 0);
        }
        l_acc[0] = __builtin_amdgcn_mfma_f32_16x16x32_bf16(ones, pf0, l_acc[0], 0, 0, 0);
        l_acc[1] = __builtin_amdgcn_mfma_f32_16x16x32_bf16(ones, pf1, l_acc[1], 0, 0, 0);
      }
      __builtin_amdgcn_s_setprio(0);
    }

    asm volatile("s_barrier" ::: "memory");
    if (kt + 2 < nktm) STAGE(BUF, kt + 2);
  };

  for (int kt = 0; kt < nktm; kt += 2) {
    TILE(0, kt);
    TILE(1, kt + 1);
  }

  // epilogue: l complete per lane (ones-MFMA) -> no cross-lane reduce
#pragma unroll
  for (int n = 0; n < 2; ++n) {
    float inv = 1.0f / l_acc[n][0];
    const int q = q0 + n * 16 + lq;
#pragma unroll
    for (int nd = 0; nd < 4; ++nd) {
      u16x4 yv;
#pragma unroll
      for (int r = 0; r < 4; ++r) yv[r] = bfc(o[nd][n][r] * inv);
      *reinterpret_cast<u16x4*>(
          Y + ((size_t)(b * TT + q)) * CC + h * DD + nd * 16 + g * 4) = yv;
    }
  }
}

extern "C" void kernel_launch(void* const* d_in, const int* in_sizes, int n_in,
                              void* d_out, int out_size, void* d_ws, size_t ws_size,
                              hipStream_t stream) {
  const float* x  = (const float*)d_in[0];
  const int*   am = (const int*)d_in[1];
  const float* Wq = (const float*)d_in[2];
  const float* bq = (const float*)d_in[3];
  const float* Wk = (const float*)d_in[4];
  const float* bk = (const float*)d_in[5];
  const float* Wv = (const float*)d_in[6];
  const float* bv = (const float*)d_in[7];
  const float* Wp = (const float*)d_in[8];
  const float* bp = (const float*)d_in[9];
  float* out = (float*)d_out;

  char* ws = (char*)d_ws;
  u16* xb    = (u16*)(ws);                        // 16 MB  [8192][1024] bf16
  u16* wqkvT = (u16*)(ws + (16ull << 20));        //  6 MB  [3072][1024] bf16 (W^T)
  u16* wpT   = (u16*)(ws + (22ull << 20));        //  2 MB  [1024][1024] bf16 (Wp^T)
  u16* qw    = (u16*)(ws + (24ull << 20));        // 16 MB  [B,H,T,D] bf16 (pre-scaled)
  u16* kw    = (u16*)(ws + (40ull << 20));        // 16 MB  [B,H,T,D] bf16
  u16* vw    = (u16*)(ws + (56ull << 20));        // 16 MB  [B,H,D,T] bf16 (transposed!)
  u16* yb    = (u16*)(ws + (72ull << 20));        // 16 MB  [B,T,C] bf16
  float* gm  = (float*)d_out;                     // 32 KB [B][T] additive mask (dead until proj)
  u32* fwords = (u32*)((char*)d_out + (64ull << 10));  // [B] chunk-valid bitmask

  prep_kernel<<<dim3(8196), 256, 0, stream>>>(
      x, am, Wq, Wk, Wv, Wp, xb, wqkvT, wpT, gm, fwords);
  qkv_gemm_kernel<<<dim3(32, 12), 512, 0, stream>>>(
      xb, wqkvT, bq, bk, bv, qw, kw, vw);
  attn_kernel<<<dim3(1024), 256, 0, stream>>>(qw, kw, vw, gm, fwords, yb);
  proj_gemm_kernel<<<dim3(64, 8), 256, 0, stream>>>(yb, wpT, bp, out);
}

// Round 11
// 167.756 us; speedup vs baseline: 1.8882x; 1.0370x over previous
//
#include <hip/hip_runtime.h>

#define BB 4
#define TT 2048
#define CC 1024
#define HH 16
#define DD 64

typedef unsigned short u16;
typedef unsigned int u32;
typedef __bf16 bf16;
typedef __attribute__((ext_vector_type(8))) bf16 bf16x8;
typedef __attribute__((ext_vector_type(8))) u16 u16x8;
typedef __attribute__((ext_vector_type(4))) u16 u16x4;
typedef __attribute__((ext_vector_type(4))) float f32x4;

static __device__ __forceinline__ u16 f2b(float f) {
  unsigned u = __builtin_bit_cast(unsigned, f);
  u += 0x7fffu + ((u >> 16) & 1u);
  return (u16)(u >> 16);
}
static __device__ __forceinline__ u16 bfc(float f) {
  return __builtin_bit_cast(u16, (__bf16)f);
}
static __device__ __forceinline__ float max3f(float a, float b, float c) {
  float d;
  asm("v_max3_f32 %0, %1, %2, %3" : "=v"(d) : "v"(a), "v"(b), "v"(c));
  return d;
}

// ---- fused prep: [0,4096) cvt x->bf16 | [4096,8192) transpose W | [8192,8196) mask ----
__global__ __launch_bounds__(256) void prep_kernel(
    const float* __restrict__ x, const int* __restrict__ am,
    const float* __restrict__ w0, const float* __restrict__ w1,
    const float* __restrict__ w2, const float* __restrict__ w3,
    u16* __restrict__ xb, u16* __restrict__ wqkvT, u16* __restrict__ wpT,
    float* __restrict__ gm, u32* __restrict__ fwords) {
  __shared__ float t[32][33];
  const int bid = blockIdx.x, tid = threadIdx.x;
  if (bid < 4096) {
    int i = bid * 256 + tid;
    const float4* p4 = reinterpret_cast<const float4*>(x) + (size_t)i * 2;
    float4 a = p4[0], b = p4[1];
    u16x8 o;
    o[0] = f2b(a.x); o[1] = f2b(a.y); o[2] = f2b(a.z); o[3] = f2b(a.w);
    o[4] = f2b(b.x); o[5] = f2b(b.y); o[6] = f2b(b.z); o[7] = f2b(b.w);
    *reinterpret_cast<u16x8*>(xb + (size_t)i * 8) = o;
  } else if (bid < 8192) {
    int r2 = bid - 4096;
    int z = r2 >> 10, rem = r2 & 1023;
    int k0 = (rem & 31) * 32, n0 = (rem >> 5) * 32;
    const float* src = z == 0 ? w0 : z == 1 ? w1 : z == 2 ? w2 : w3;
    u16* dst = z < 3 ? wqkvT + (size_t)z * CC * CC : wpT;
    int tx = tid & 31, ty = tid >> 5;
#pragma unroll
    for (int i = 0; i < 4; ++i)
      t[ty + i * 8][tx] = src[(size_t)(k0 + ty + i * 8) * CC + n0 + tx];
    __syncthreads();
#pragma unroll
    for (int i = 0; i < 4; ++i)
      dst[(size_t)(n0 + ty + i * 8) * CC + k0 + tx] = f2b(t[tx][ty + i * 8]);
  } else {
    __shared__ u32 sf[32];
    int b = bid - 8192;
    int lane = tid & 63, w = tid >> 6;
#pragma unroll
    for (int j = 0; j < 8; ++j) {
      int c = w * 8 + j;
      int i = c * 64 + lane;
      int v = am[b * TT + i];
      gm[b * TT + i] = v ? 0.f : -1e30f;
      unsigned long long bal = __ballot(v != 0);
      if (lane == 0) sf[c] = (bal == ~0ull) ? 1u : 0u;
    }
    __syncthreads();
    if (tid == 0) {
      u32 fw = 0;
      for (int c = 0; c < 32; ++c) fw |= sf[c] << c;
      fwords[b] = fw;
    }
  }
}

// ------------- QKV GEMM: 256x256, BK=64, 8 waves, 4-phase/K-tile interleave -------------
// Per phase: {vmcnt(4); barrier; ds_read quadrant; stage 1 chunk of t+1; lgkmcnt(0);
// 16 MFMA}. Chunks consumption-ordered (c1=A first-halves, c2=B first-quads, c3=B
// second-quads, c4=A second-halves) -> each chunk ~4 phases in flight; vmcnt never 0
// in steady state (drain 4->2->0 on last tile only). XOR-swizzled LDS (both sides).
__global__ __launch_bounds__(512, 2) void qkv_gemm_kernel(
    const u16* __restrict__ A, const u16* __restrict__ Bt,
    const float* __restrict__ bq, const float* __restrict__ bk, const float* __restrict__ bv,
    u16* __restrict__ q_out, u16* __restrict__ k_out, u16* __restrict__ v_out) {
  __shared__ __align__(16) char LDS[131072];
  const int tid = threadIdx.x, lane = tid & 63, w = tid >> 6;
  const int wm = w >> 2, wn = w & 3;
  const int lq = lane & 15, g = lane >> 4;
  const int m0 = blockIdx.x * 256, n0 = blockIdx.y * 256;

  const int l3 = lane >> 3;
  const int swb = ((lane & 7) ^ (l3 & 7)) * 16;  // inverse-swizzled source column

  // one chunk-half = 1 global_load_lds/thread = 64 rows (8 rows/wave, contiguous LDS)
  auto LOAD_A = [&](int db, int R, int ko) {
    int rb = R + w * 8;
    __builtin_amdgcn_global_load_lds(
        (const __attribute__((address_space(1))) void*)(
            (const char*)A + (size_t)(m0 + rb + l3) * 2048 + ko + swb),
        (__attribute__((address_space(3))) void*)(LDS + db * 32768 + rb * 128), 16, 0, 0);
  };
  auto LOAD_B = [&](int db, int R, int sub, int ko) {
    int rb = R + (w >> 2) * 64 + (w & 3) * 8 + sub;
    __builtin_amdgcn_global_load_lds(
        (const __attribute__((address_space(1))) void*)(
            (const char*)Bt + (size_t)(n0 + rb + l3) * 2048 + ko + swb),
        (__attribute__((address_space(3))) void*)(LDS + 65536 + db * 32768 + rb * 128), 16, 0, 0);
  };
  auto C1 = [&](int db, int ko) { LOAD_A(db, 0, ko); LOAD_A(db, 128, ko); };
  auto C2 = [&](int db, int ko) { LOAD_B(db, 0, 0, ko); LOAD_B(db, 128, 0, ko); };
  auto C3 = [&](int db, int ko) { LOAD_B(db, 0, 32, ko); LOAD_B(db, 128, 32, ko); };
  auto C4 = [&](int db, int ko) { LOAD_A(db, 64, ko); LOAD_A(db, 192, ko); };

  const int acol0 = (g * 16) ^ ((lq & 7) << 4);
  const int acol1 = (64 + g * 16) ^ ((lq & 7) << 4);
  const int aBase = wm * 16384 + lq * 128;
  const int bBase = 65536 + wn * 8192 + lq * 128;

  f32x4 acc[8][4] = {};
  bf16x8 af[4][2], bf[2][2];

  // prologue: tile 0's 4 chunks (8 loads outstanding)
  C1(0, 0); C2(0, 0); C3(0, 0); C4(0, 0);

  for (int t = 0; t < 16; ++t) {
    const int db = t & 1, dn = db ^ 1;
    const int ko = (t + 1) * 128;
    const bool st = t < 15;
    const char* la = LDS + db * 32768 + aBase;
    const char* lb = LDS + db * 32768 + bBase;

    // ---- P1: A m0-3 + B j0-1 ----
    asm volatile("s_waitcnt vmcnt(4)" ::: "memory");
    asm volatile("s_barrier" ::: "memory");
#pragma unroll
    for (int i = 0; i < 4; ++i) {
      af[i][0] = *reinterpret_cast<const bf16x8*>(la + i * 2048 + acol0);
      af[i][1] = *reinterpret_cast<const bf16x8*>(la + i * 2048 + acol1);
    }
#pragma unroll
    for (int j = 0; j < 2; ++j) {
      bf[j][0] = *reinterpret_cast<const bf16x8*>(lb + j * 2048 + acol0);
      bf[j][1] = *reinterpret_cast<const bf16x8*>(lb + j * 2048 + acol1);
    }
    if (st) C1(dn, ko);
    asm volatile("s_waitcnt lgkmcnt(0)" ::: "memory");
    __builtin_amdgcn_sched_barrier(0);
    __builtin_amdgcn_s_setprio(1);
#pragma unroll
    for (int i = 0; i < 4; ++i)
#pragma unroll
      for (int j = 0; j < 2; ++j) {
        acc[i][j] = __builtin_amdgcn_mfma_f32_16x16x32_bf16(af[i][0], bf[j][0], acc[i][j], 0, 0, 0);
        acc[i][j] = __builtin_amdgcn_mfma_f32_16x16x32_bf16(af[i][1], bf[j][1], acc[i][j], 0, 0, 0);
      }
    __builtin_amdgcn_s_setprio(0);

    // ---- P2: B j2-3 ----
    if (st) asm volatile("s_waitcnt vmcnt(4)" ::: "memory");
    else    asm volatile("s_waitcnt vmcnt(2)" ::: "memory");
    asm volatile("s_barrier" ::: "memory");
#pragma unroll
    for (int j = 0; j < 2; ++j) {
      bf[j][0] = *reinterpret_cast<const bf16x8*>(lb + (2 + j) * 2048 + acol0);
      bf[j][1] = *reinterpret_cast<const bf16x8*>(lb + (2 + j) * 2048 + acol1);
    }
    if (st) C2(dn, ko);
    asm volatile("s_waitcnt lgkmcnt(0)" ::: "memory");
    __builtin_amdgcn_sched_barrier(0);
    __builtin_amdgcn_s_setprio(1);
#pragma unroll
    for (int i = 0; i < 4; ++i)
#pragma unroll
      for (int j = 0; j < 2; ++j) {
        acc[i][2 + j] = __builtin_amdgcn_mfma_f32_16x16x32_bf16(af[i][0], bf[j][0], acc[i][2 + j], 0, 0, 0);
        acc[i][2 + j] = __builtin_amdgcn_mfma_f32_16x16x32_bf16(af[i][1], bf[j][1], acc[i][2 + j], 0, 0, 0);
      }
    __builtin_amdgcn_s_setprio(0);

    // ---- P3: A m4-7 + re-read B j0-1 ----
    if (st) asm volatile("s_waitcnt vmcnt(4)" ::: "memory");
    else    asm volatile("s_waitcnt vmcnt(0)" ::: "memory");
    asm volatile("s_barrier" ::: "memory");
#pragma unroll
    for (int i = 0; i < 4; ++i) {
      af[i][0] = *reinterpret_cast<const bf16x8*>(la + (4 + i) * 2048 + acol0);
      af[i][1] = *reinterpret_cast<const bf16x8*>(la + (4 + i) * 2048 + acol1);
    }
#pragma unroll
    for (int j = 0; j < 2; ++j) {
      bf[j][0] = *reinterpret_cast<const bf16x8*>(lb + j * 2048 + acol0);
      bf[j][1] = *reinterpret_cast<const bf16x8*>(lb + j * 2048 + acol1);
    }
    if (st) C3(dn, ko);
    asm volatile("s_waitcnt lgkmcnt(0)" ::: "memory");
    __builtin_amdgcn_sched_barrier(0);
    __builtin_amdgcn_s_setprio(1);
#pragma unroll
    for (int i = 0; i < 4; ++i)
#pragma unroll
      for (int j = 0; j < 2; ++j) {
        acc[4 + i][j] = __builtin_amdgcn_mfma_f32_16x16x32_bf16(af[i][0], bf[j][0], acc[4 + i][j], 0, 0, 0);
        acc[4 + i][j] = __builtin_amdgcn_mfma_f32_16x16x32_bf16(af[i][1], bf[j][1], acc[4 + i][j], 0, 0, 0);
      }
    __builtin_amdgcn_s_setprio(0);

    // ---- P4: re-read B j2-3 ----
    asm volatile("s_barrier" ::: "memory");
#pragma unroll
    for (int j = 0; j < 2; ++j) {
      bf[j][0] = *reinterpret_cast<const bf16x8*>(lb + (2 + j) * 2048 + acol0);
      bf[j][1] = *reinterpret_cast<const bf16x8*>(lb + (2 + j) * 2048 + acol1);
    }
    if (st) C4(dn, ko);
    asm volatile("s_waitcnt lgkmcnt(0)" ::: "memory");
    __builtin_amdgcn_sched_barrier(0);
    __builtin_amdgcn_s_setprio(1);
#pragma unroll
    for (int i = 0; i < 4; ++i)
#pragma unroll
      for (int j = 0; j < 2; ++j) {
        acc[4 + i][2 + j] = __builtin_amdgcn_mfma_f32_16x16x32_bf16(af[i][0], bf[j][0], acc[4 + i][2 + j], 0, 0, 0);
        acc[4 + i][2 + j] = __builtin_amdgcn_mfma_f32_16x16x32_bf16(af[i][1], bf[j][1], acc[4 + i][2 + j], 0, 0, 0);
      }
    __builtin_amdgcn_s_setprio(0);
  }

  // epilogue
  const int g3 = n0 >> 10;  // 0:Q 1:K 2:V (uniform per block)
  const int mrow = m0 + wm * 128;
  const int ncol = n0 + wn * 64;
  if (g3 < 2) {
    u16* dst = g3 == 0 ? q_out : k_out;
    const float* bias = g3 == 0 ? bq : bk;
    const float scl = g3 == 0 ? 0.18033688f : 1.0f;  // Q pre-scale: 0.125*log2(e)
#pragma unroll
    for (int i = 0; i < 8; ++i)
#pragma unroll
      for (int j = 0; j < 4; ++j) {
        int n = ncol + j * 16 + lq;
        int h = (n >> 6) & 15, d = n & 63;
        float bb = bias[n & 1023];
#pragma unroll
        for (int r = 0; r < 4; ++r) {
          int m = mrow + i * 16 + g * 4 + r;
          int b = m >> 11, t = m & 2047;
          dst[(((size_t)(b * HH + h)) * TT + t) * DD + d] = f2b((acc[i][j][r] + bb) * scl);
        }
      }
  } else {
#pragma unroll
    for (int i = 0; i < 8; ++i)
#pragma unroll
      for (int j = 0; j < 4; ++j) {
        int n = ncol + j * 16 + lq;
        int h = (n >> 6) & 15, d = n & 63;
        float bb = bv[n & 1023];
        int mb = mrow + i * 16 + g * 4;
        int b = mb >> 11, t = mb & 2047;
        u16x4 vv;
#pragma unroll
        for (int r = 0; r < 4; ++r) vv[r] = f2b(acc[i][j][r] + bb);
        *reinterpret_cast<u16x4*>(v_out + (((size_t)(b * HH + h)) * DD + d) * TT + t) = vv;
      }
  }
}

// -------- proj GEMM: 128x128, BK=64, dbuf swizzled LDS + counted vmcnt, 2 blk/CU --------
__global__ __launch_bounds__(256) void proj_gemm_kernel(
    const u16* __restrict__ A, const u16* __restrict__ Bt,
    const float* __restrict__ bias, float* __restrict__ f_out) {
  __shared__ __align__(16) char LDS[65536];  // A[2][128*64] | B[2][128*64] bf16
  const int tid = threadIdx.x, lane = tid & 63, w = tid >> 6;
  const int wm = w >> 1, wn = w & 1;
  const int lq = lane & 15, g = lane >> 4;
  const int m0 = blockIdx.x * 128, n0 = blockIdx.y * 128;
  const int l3 = lane >> 3;
  const int swb = ((lane & 7) ^ (l3 & 7)) * 16;
  f32x4 acc[4][4] = {};

  auto STAGE = [&](int db, int kt) {
    const int ko = kt * 128;
#pragma unroll
    for (int r = 0; r < 4; ++r) {
      int rb = r * 32 + w * 8;
      __builtin_amdgcn_global_load_lds(
          (const __attribute__((address_space(1))) void*)(
              (const char*)A + (size_t)(m0 + rb + l3) * 2048 + ko + swb),
          (__attribute__((address_space(3))) void*)(LDS + db * 16384 + rb * 128), 16, 0, 0);
      __builtin_amdgcn_global_load_lds(
          (const __attribute__((address_space(1))) void*)(
              (const char*)Bt + (size_t)(n0 + rb + l3) * 2048 + ko + swb),
          (__attribute__((address_space(3))) void*)(LDS + 32768 + db * 16384 + rb * 128), 16, 0, 0);
    }
  };

  const int acol0 = (g * 16) ^ ((lq & 7) << 4);
  const int acol1 = (64 + g * 16) ^ ((lq & 7) << 4);
  const int aBase = wm * 8192 + lq * 128;
  const int bBase = 32768 + wn * 8192 + lq * 128;

  STAGE(0, 0);
  STAGE(1, 1);
  for (int kt = 0; kt < 16; ++kt) {
    if (kt == 15) asm volatile("s_waitcnt vmcnt(0)" ::: "memory");
    else          asm volatile("s_waitcnt vmcnt(8)" ::: "memory");
    asm volatile("s_barrier" ::: "memory");
    const int db = kt & 1;
    const char* la = LDS + db * 16384 + aBase;
    const char* lb = LDS + db * 16384 + bBase;
    bf16x8 af[4][2], bfr[4][2];
#pragma unroll
    for (int i = 0; i < 4; ++i) {
      af[i][0] = *reinterpret_cast<const bf16x8*>(la + i * 2048 + acol0);
      af[i][1] = *reinterpret_cast<const bf16x8*>(la + i * 2048 + acol1);
      bfr[i][0] = *reinterpret_cast<const bf16x8*>(lb + i * 2048 + acol0);
      bfr[i][1] = *reinterpret_cast<const bf16x8*>(lb + i * 2048 + acol1);
    }
    asm volatile("s_waitcnt lgkmcnt(0)" ::: "memory");
    __builtin_amdgcn_sched_barrier(0);
    __builtin_amdgcn_s_setprio(1);
#pragma unroll
    for (int i = 0; i < 4; ++i)
#pragma unroll
      for (int j = 0; j < 4; ++j) {
        acc[i][j] = __builtin_amdgcn_mfma_f32_16x16x32_bf16(af[i][0], bfr[j][0], acc[i][j], 0, 0, 0);
        acc[i][j] = __builtin_amdgcn_mfma_f32_16x16x32_bf16(af[i][1], bfr[j][1], acc[i][j], 0, 0, 0);
      }
    __builtin_amdgcn_s_setprio(0);
    asm volatile("s_barrier" ::: "memory");
    if (kt + 2 < 16) STAGE(db, kt + 2);
  }

  const int mrow = m0 + wm * 64;
  const int ncol = n0 + wn * 64;
#pragma unroll
  for (int i = 0; i < 4; ++i)
#pragma unroll
    for (int j = 0; j < 4; ++j)
#pragma unroll
      for (int r = 0; r < 4; ++r) {
        int m = mrow + i * 16 + g * 4 + r;
        int n = ncol + j * 16 + lq;
        f_out[(size_t)m * CC + n] = acc[i][j][r] + bias[n];
      }
}

// ------- causal flash attention: LDS-staged K/V dbuf + counted vmcnt (r10, validated) -------
__global__ __launch_bounds__(256, 2) void attn_kernel(
    const u16* __restrict__ Q, const u16* __restrict__ K, const u16* __restrict__ Vt,
    const float* __restrict__ gm, const u32* __restrict__ fwords, u16* __restrict__ Y) {
  __shared__ __align__(16) char LDS[51200];
  const int flat = blockIdx.x;
  const int xcd = flat & 7, idx = flat >> 3;
  const int bh = xcd * 8 + (idx & 7);
  const int jb = 15 - (idx >> 3);
  const int b = bh >> 4, h = bh & 15;
  const int tid = threadIdx.x, lane = tid & 63, w = tid >> 6;
  const int lq = lane & 15, g = lane >> 4;
  const int qt = 4 * jb + w;
  const int q0 = qt * 32;
  const int nkt = (qt >> 1) + 1;
  const int nktm = 2 * jb + 2;
  const u32 fw = fwords[b];

  const u16* Qb = Q + (size_t)bh * TT * DD;
  const char* Kb = (const char*)(K + (size_t)bh * TT * DD);
  const char* Vb = (const char*)(Vt + (size_t)bh * DD * TT);

  const int l3 = lane >> 3, l7 = lane & 7;
  const int swb = (l7 * 16) ^ (l3 << 4);
  const char* kp0 = Kb + (2 * w + 0) * 1024 + l3 * 128 + swb;
  const char* kp1 = Kb + (2 * w + 1) * 1024 + l3 * 128 + swb;
  const char* vp0 = Vb + (size_t)((2 * w + 0) * 8 + l3) * 4096 + swb;
  const char* vp1 = Vb + (size_t)((2 * w + 1) * 8 + l3) * 4096 + swb;

  const int sw2 = (lq & 7) << 4;
  const int fb0 = lq * 128 + ((g * 16) ^ sw2);
  const int fb1 = lq * 128 + (((64) + g * 16) ^ sw2);
  const int pwb = 32768 + w * 4608 + lq * 144 + g * 8;
  const int prb = 32768 + w * 4608 + lq * 144 + g * 16;

  auto STAGE = [&](int buf, int kt2) {
    const int ko = kt2 * 8192, vo = kt2 * 128, lb = buf * 8192;
    __builtin_amdgcn_global_load_lds(
        (const __attribute__((address_space(1))) void*)(kp0 + ko),
        (__attribute__((address_space(3))) void*)(LDS + lb + (2 * w + 0) * 1024), 16, 0, 0);
    __builtin_amdgcn_global_load_lds(
        (const __attribute__((address_space(1))) void*)(kp1 + ko),
        (__attribute__((address_space(3))) void*)(LDS + lb + (2 * w + 1) * 1024), 16, 0, 0);
    __builtin_amdgcn_global_load_lds(
        (const __attribute__((address_space(1))) void*)(vp0 + vo),
        (__attribute__((address_space(3))) void*)(LDS + 16384 + lb + (2 * w + 0) * 1024), 16, 0, 0);
    __builtin_amdgcn_global_load_lds(
        (const __attribute__((address_space(1))) void*)(vp1 + vo),
        (__attribute__((address_space(3))) void*)(LDS + 16384 + lb + (2 * w + 1) * 1024), 16, 0, 0);
  };

  bf16x8 qf[2][2];
#pragma unroll
  for (int n = 0; n < 2; ++n)
#pragma unroll
    for (int ks = 0; ks < 2; ++ks)
      qf[n][ks] = *reinterpret_cast<const bf16x8*>(
          Qb + (size_t)(q0 + n * 16 + lq) * DD + ks * 32 + g * 8);

  const u16x8 onesu = {0x3F80, 0x3F80, 0x3F80, 0x3F80, 0x3F80, 0x3F80, 0x3F80, 0x3F80};
  const bf16x8 ones = __builtin_bit_cast(bf16x8, onesu);

  f32x4 o[4][2] = {};
  f32x4 l_acc[2] = {};
  float mrun[2] = {-1e30f, -1e30f};
  const f32x4 z4 = {0.f, 0.f, 0.f, 0.f};

  STAGE(0, 0);
  STAGE(1, 1);

  auto TILE = [&](int BUF, int kt) {
    if (kt < nktm - 1)
      asm volatile("s_waitcnt vmcnt(4)" ::: "memory");
    else
      asm volatile("s_waitcnt vmcnt(0)" ::: "memory");
    asm volatile("s_barrier" ::: "memory");

    if (kt < nkt) {
      const int kv0 = kt * 64;
      bf16x8 kf0[4], kf1[4];
#pragma unroll
      for (int m = 0; m < 4; ++m) {
        kf0[m] = *reinterpret_cast<const bf16x8*>(LDS + BUF * 8192 + m * 2048 + fb0);
        kf1[m] = *reinterpret_cast<const bf16x8*>(LDS + BUF * 8192 + m * 2048 + fb1);
      }
      f32x4 s[4][2];
      __builtin_amdgcn_s_setprio(1);
#pragma unroll
      for (int m = 0; m < 4; ++m)
#pragma unroll
        for (int n = 0; n < 2; ++n) {
          s[m][n] = __builtin_amdgcn_mfma_f32_16x16x32_bf16(kf0[m], qf[n][0], z4, 0, 0, 0);
          s[m][n] = __builtin_amdgcn_mfma_f32_16x16x32_bf16(kf1[m], qf[n][1], s[m][n], 0, 0, 0);
        }
      __builtin_amdgcn_s_setprio(0);

      if (!((fw >> kt) & 1u)) {
#pragma unroll
        for (int m = 0; m < 4; ++m) {
          float4 mv = *reinterpret_cast<const float4*>(gm + b * TT + kv0 + m * 16 + g * 4);
#pragma unroll
          for (int n = 0; n < 2; ++n) {
            s[m][n][0] += mv.x; s[m][n][1] += mv.y;
            s[m][n][2] += mv.z; s[m][n][3] += mv.w;
          }
        }
      }
      if (kt == nkt - 1) {
#pragma unroll
        for (int n = 0; n < 2; ++n) {
          const int q = q0 + n * 16 + lq;
#pragma unroll
          for (int m = 0; m < 4; ++m)
#pragma unroll
            for (int r = 0; r < 4; ++r) {
              int kv = kv0 + m * 16 + g * 4 + r;
              s[m][n][r] = (kv <= q) ? s[m][n][r] : -1e30f;
            }
        }
      }

#pragma unroll
      for (int n = 0; n < 2; ++n) {
        float m1 = max3f(s[0][n][0], s[0][n][1], s[0][n][2]);
        float m2 = max3f(s[0][n][3], s[1][n][0], s[1][n][1]);
        float m3 = max3f(s[1][n][2], s[1][n][3], s[2][n][0]);
        float m4 = max3f(s[2][n][1], s[2][n][2], s[2][n][3]);
        float m5 = max3f(s[3][n][0], s[3][n][1], s[3][n][2]);
        float rm = fmaxf(max3f(m1, m2, m3), max3f(m4, m5, s[3][n][3]));
        if (!__all(rm <= mrun[n] + 8.f)) {
          float rg = fmaxf(rm, __shfl_xor(rm, 16));
          rg = fmaxf(rg, __shfl_xor(rg, 32));
          float mnew = fmaxf(mrun[n], rg);
          float corr = __builtin_exp2f(mrun[n] - mnew);
          mrun[n] = mnew;
          l_acc[n] *= corr;
#pragma unroll
          for (int nd = 0; nd < 4; ++nd)
#pragma unroll
            for (int r = 0; r < 4; ++r) o[nd][n][r] *= corr;
        }
        const float mn = mrun[n];
#pragma unroll
        for (int m = 0; m < 4; ++m) {
          float p0 = __builtin_exp2f(s[m][n][0] - mn);
          float p1 = __builtin_exp2f(s[m][n][1] - mn);
          float p2 = __builtin_exp2f(s[m][n][2] - mn);
          float p3 = __builtin_exp2f(s[m][n][3] - mn);
          u32 wa, wb;
          asm("v_cvt_pk_bf16_f32 %0, %1, %2" : "=v"(wa) : "v"(p0), "v"(p1));
          asm("v_cvt_pk_bf16_f32 %0, %1, %2" : "=v"(wb) : "v"(p2), "v"(p3));
          uint2 pw; pw.x = wa; pw.y = wb;
          *reinterpret_cast<uint2*>(LDS + pwb + n * 2304 + m * 32) = pw;
        }
      }

      asm volatile("s_waitcnt lgkmcnt(0)" ::: "memory");
      __builtin_amdgcn_sched_barrier(0);

      __builtin_amdgcn_s_setprio(1);
#pragma unroll
      for (int ks = 0; ks < 2; ++ks) {
        const int fb = ks ? fb1 : fb0;
        bf16x8 pf0 = *reinterpret_cast<const bf16x8*>(LDS + prb + 0 * 2304 + ks * 64);
        bf16x8 pf1 = *reinterpret_cast<const bf16x8*>(LDS + prb + 1 * 2304 + ks * 64);
#pragma unroll
        for (int nd = 0; nd < 4; ++nd) {
          bf16x8 vf = *reinterpret_cast<const bf16x8*>(LDS + 16384 + BUF * 8192 + nd * 2048 + fb);
          o[nd][0] = __builtin_amdgcn_mfma_f32_16x16x32_bf16(vf, pf0, o[nd][0], 0, 0, 0);
          o[nd][1] = __builtin_amdgcn_mfma_f32_16x16x32_bf16(vf, pf1, o[nd][1], 0, 0, 0);
        }
        l_acc[0] = __builtin_amdgcn_mfma_f32_16x16x32_bf16(ones, pf0, l_acc[0], 0, 0, 0);
        l_acc[1] = __builtin_amdgcn_mfma_f32_16x16x32_bf16(ones, pf1, l_acc[1], 0, 0, 0);
      }
      __builtin_amdgcn_s_setprio(0);
    }

    asm volatile("s_barrier" ::: "memory");
    if (kt + 2 < nktm) STAGE(BUF, kt + 2);
  };

  for (int kt = 0; kt < nktm; kt += 2) {
    TILE(0, kt);
    TILE(1, kt + 1);
  }

#pragma unroll
  for (int n = 0; n < 2; ++n) {
    float inv = 1.0f / l_acc[n][0];
    const int q = q0 + n * 16 + lq;
#pragma unroll
    for (int nd = 0; nd < 4; ++nd) {
      u16x4 yv;
#pragma unroll
      for (int r = 0; r < 4; ++r) yv[r] = bfc(o[nd][n][r] * inv);
      *reinterpret_cast<u16x4*>(
          Y + ((size_t)(b * TT + q)) * CC + h * DD + nd * 16 + g * 4) = yv;
    }
  }
}

extern "C" void kernel_launch(void* const* d_in, const int* in_sizes, int n_in,
                              void* d_out, int out_size, void* d_ws, size_t ws_size,
                              hipStream_t stream) {
  const float* x  = (const float*)d_in[0];
  const int*   am = (const int*)d_in[1];
  const float* Wq = (const float*)d_in[2];
  const float* bq = (const float*)d_in[3];
  const float* Wk = (const float*)d_in[4];
  const float* bk = (const float*)d_in[5];
  const float* Wv = (const float*)d_in[6];
  const float* bv = (const float*)d_in[7];
  const float* Wp = (const float*)d_in[8];
  const float* bp = (const float*)d_in[9];
  float* out = (float*)d_out;

  char* ws = (char*)d_ws;
  u16* xb    = (u16*)(ws);                        // 16 MB  [8192][1024] bf16
  u16* wqkvT = (u16*)(ws + (16ull << 20));        //  6 MB  [3072][1024] bf16 (W^T)
  u16* wpT   = (u16*)(ws + (22ull << 20));        //  2 MB  [1024][1024] bf16 (Wp^T)
  u16* qw    = (u16*)(ws + (24ull << 20));        // 16 MB  [B,H,T,D] bf16 (pre-scaled)
  u16* kw    = (u16*)(ws + (40ull << 20));        // 16 MB  [B,H,T,D] bf16
  u16* vw    = (u16*)(ws + (56ull << 20));        // 16 MB  [B,H,D,T] bf16 (transposed!)
  u16* yb    = (u16*)(ws + (72ull << 20));        // 16 MB  [B,T,C] bf16
  float* gm  = (float*)d_out;                     // 32 KB [B][T] additive mask (dead until proj)
  u32* fwords = (u32*)((char*)d_out + (64ull << 10));  // [B] chunk-valid bitmask

  prep_kernel<<<dim3(8196), 256, 0, stream>>>(
      x, am, Wq, Wk, Wv, Wp, xb, wqkvT, wpT, gm, fwords);
  qkv_gemm_kernel<<<dim3(32, 12), 512, 0, stream>>>(
      xb, wqkvT, bq, bk, bv, qw, kw, vw);
  attn_kernel<<<dim3(1024), 256, 0, stream>>>(qw, kw, vw, gm, fwords, yb);
  proj_gemm_kernel<<<dim3(64, 8), 256, 0, stream>>>(yb, wpT, bp, out);
}